// Round 1
// baseline (936.731 us; speedup 1.0000x reference)
//
#include <hip/hip_runtime.h>
#include <stdint.h>

typedef unsigned long long u64;
typedef unsigned int u32;

#define NUM_B 32
#define NUM_P 76800
#define TOPK 1500
#define NBINS 16384
#define CAP 2048
#define NWORDS 24  // ceil(1536/64) bit-words for active mask

__device__ __forceinline__ u32 fbits(float f) { return __float_as_uint(f); }

// ---------------- zero out + histogram scratch ----------------
__global__ void zero_kernel(u32* a, int n, u32* b, int nb) {
    int i = blockIdx.x * blockDim.x + threadIdx.x;
    int stride = gridDim.x * blockDim.x;
    for (int t = i; t < n; t += stride) a[t] = 0;
    for (int t = i; t < nb; t += stride) b[t] = 0;
}

// ---------------- histogram of class-1 score bits (top 16 bits) ----------------
__global__ void hist_kernel(const float* __restrict__ conf, u32* __restrict__ hist) {
    int p = blockIdx.x * blockDim.x + threadIdx.x;
    int b = blockIdx.y;
    if (p >= NUM_P) return;
    float s = conf[((size_t)b * NUM_P + p) * 2 + 1];
    if (s > 0.01f) {
        u32 bin = fbits(s) >> 16;   // s in (0.01,1) -> bin < 16384
        if (bin >= NBINS) bin = NBINS - 1;
        atomicAdd(&hist[(size_t)b * NBINS + bin], 1u);
    }
}

// ---------------- find per-batch threshold bin: smallest bin T with suffix count >= TOPK ----
__global__ void thresh_kernel(const u32* __restrict__ hist, int* __restrict__ tbin) {
    int b = blockIdx.x;
    int tid = threadIdx.x;
    __shared__ u32 vals[256];
    __shared__ int s_min;
    u32 total = 0;
    for (int c = 0; c < NBINS / 256; ++c) {
        if (tid == 0) s_min = 256;
        int bin = NBINS - 1 - (c * 256 + tid);
        u32 v = hist[(size_t)b * NBINS + bin];
        __syncthreads();        // covers s_min reset + previous-iter vals reads
        vals[tid] = v;
        __syncthreads();
        // inclusive Hillis-Steele scan over tid (suffix over bins)
        for (int off = 1; off < 256; off <<= 1) {
            u32 add = (tid >= off) ? vals[tid - off] : 0;
            __syncthreads();
            vals[tid] += add;
            __syncthreads();
        }
        u32 cum = total + vals[tid];
        if (cum >= TOPK) atomicMin(&s_min, tid);
        __syncthreads();
        if (s_min < 256) {
            if (tid == 0) tbin[b] = NBINS - 1 - (c * 256 + s_min);
            return;
        }
        total += vals[255];
    }
    if (tid == 0) tbin[b] = 0;  // fewer than TOPK candidates
}

// ---------------- compact candidate keys (score_bits<<32 | ~index) ----------------
__global__ void compact_kernel(const float* __restrict__ conf, const int* __restrict__ tbin,
                               u32* __restrict__ counts, u64* __restrict__ keys) {
    int p = blockIdx.x * blockDim.x + threadIdx.x;
    int b = blockIdx.y;
    if (p >= NUM_P) return;
    float s = conf[((size_t)b * NUM_P + p) * 2 + 1];
    if (s > 0.01f) {
        u32 bin = fbits(s) >> 16;
        if (bin >= NBINS) bin = NBINS - 1;
        if ((int)bin >= tbin[b]) {
            u32 pos = atomicAdd(&counts[b], 1u);
            if (pos < CAP) keys[(size_t)b * CAP + pos] = ((u64)fbits(s) << 32) | (u32)(~p);
        }
    }
}

// ---------------- bitonic sort 2048 keys desc, take top-1500, gather+decode boxes ----------
__global__ __launch_bounds__(256) void sort_decode_kernel(
    const u64* __restrict__ keys, const u32* __restrict__ counts,
    const float* __restrict__ loc, const float* __restrict__ prior,
    float* __restrict__ sscore, float* __restrict__ sbox) {
#pragma clang fp contract(off)
    int b = blockIdx.x, tid = threadIdx.x;
    __shared__ u64 k[CAP];
    int n = (int)min(counts[b], (u32)CAP);
    for (int t = tid; t < CAP; t += 256)
        k[t] = (t < n) ? keys[(size_t)b * CAP + t] : 0ULL;
    __syncthreads();
    for (int kk = 2; kk <= CAP; kk <<= 1) {
        for (int j = kk >> 1; j > 0; j >>= 1) {
            for (int t = tid; t < CAP; t += 256) {
                int l = t ^ j;
                if (l > t) {
                    u64 a = k[t], c = k[l];
                    bool desc = ((t & kk) == 0);
                    if (desc ? (a < c) : (a > c)) { k[t] = c; k[l] = a; }
                }
            }
            __syncthreads();
        }
    }
    for (int r = tid; r < TOPK; r += 256) {
        u64 key = k[r];
        float sc = 0.f, x1 = 0.f, y1 = 0.f, x2 = 0.f, y2 = 0.f;
        if (key != 0ULL) {
            u32 pidx = ~(u32)key;
            sc = __uint_as_float((u32)(key >> 32));
            const float* lp = &loc[((size_t)b * NUM_P + pidx) * 4];
            const float* pp = &prior[(size_t)pidx * 4];
            float lx = lp[0], ly = lp[1], lw = lp[2], lh = lp[3];
            float pcx = pp[0], pcy = pp[1], pw = pp[2], ph = pp[3];
            float cx = pcx + (lx * 0.1f) * pw;   // match np: (loc*VAR0)*prior_wh + prior_cxcy
            float cy = pcy + (ly * 0.1f) * ph;
            float w  = pw * expf(lw * 0.2f);
            float h  = ph * expf(lh * 0.2f);
            x1 = cx - w * 0.5f;
            y1 = cy - h * 0.5f;
            x2 = x1 + w;
            y2 = y1 + h;
        }
        sscore[(size_t)b * TOPK + r] = sc;
        float* bx = &sbox[((size_t)b * TOPK + r) * 4];
        bx[0] = x1; bx[1] = y1; bx[2] = x2; bx[3] = y2;
    }
}

// ---------------- greedy NMS (one block per batch) + compacted output write ----------------
__global__ __launch_bounds__(256) void nms_kernel(
    const float* __restrict__ sscore, const float* __restrict__ sbox,
    float* __restrict__ out) {
#pragma clang fp contract(off)
    int b = blockIdx.x, tid = threadIdx.x;
    __shared__ float bx1[TOPK], by1[TOPK], bx2[TOPK], by2[TOPK], bar[TOPK], bsc[TOPK];
    __shared__ u64 act[NWORDS];
    __shared__ int s_next;
    __shared__ short keep_list[TOPK];

    for (int r = tid; r < TOPK; r += 256) {
        float sc = sscore[(size_t)b * TOPK + r];
        const float* bp = &sbox[((size_t)b * TOPK + r) * 4];
        float x1 = bp[0], y1 = bp[1], x2 = bp[2], y2 = bp[3];
        bx1[r] = x1; by1[r] = y1; bx2[r] = x2; by2[r] = y2;
        bar[r] = (x2 - x1) * (y2 - y1);
        bsc[r] = sc;
    }
    if (tid < NWORDS) act[tid] = 0ULL;
    __syncthreads();
    // build active bitmask via wave ballots (valid = real candidate, score>0)
    for (int c = 0; c < 6; ++c) {
        int r = c * 256 + tid;
        bool v = (r < TOPK) && (bsc[r] > 0.0f);
        u64 m = __ballot(v);
        if ((tid & 63) == 0) act[c * 4 + (tid >> 6)] = m;
    }
    __syncthreads();

    int i = 0;
    int kcnt = 0;
    while (true) {
        if (tid == 0) {
            int w = i >> 6;
            int found = TOPK;
            u64 word = act[w] & (~0ULL << (i & 63));
            while (true) {
                if (word) { found = (w << 6) + __ffsll(word) - 1; break; }
                ++w;
                if (w >= NWORDS) break;
                word = act[w];
            }
            s_next = found;
        }
        __syncthreads();
        i = s_next;
        if (i >= TOPK) break;
        if (tid == 0) keep_list[kcnt] = (short)i;
        kcnt++;
        float x1i = bx1[i], y1i = by1[i], x2i = bx2[i], y2i = by2[i], ai = bar[i];
        for (int r = i + 1 + tid; r < TOPK; r += 256) {
            int w = r >> 6;
            u64 bit = 1ULL << (r & 63);
            if (act[w] & bit) {
                float xx1 = fmaxf(bx1[r], x1i);
                float yy1 = fmaxf(by1[r], y1i);
                float xx2 = fminf(bx2[r], x2i);
                float yy2 = fminf(by2[r], y2i);
                float iw = fmaxf(xx2 - xx1, 0.0f);
                float ih = fmaxf(yy2 - yy1, 0.0f);
                float inter = iw * ih;
                float denom = (bar[r] + ai) - inter;
                float iou = inter / denom;
                if (iou > 0.2f) atomicAnd(&act[w], ~bit);
            }
        }
        i = i + 1;
        __syncthreads();
    }
    // kept rows -> out[b][1][r][0..4]; everything else already zeroed
    for (int r = tid; r < kcnt; r += 256) {
        int idx = keep_list[r];
        size_t base = (((size_t)b * 2 + 1) * TOPK + (size_t)r) * 5;
        out[base + 0] = bsc[idx];
        out[base + 1] = bx1[idx];
        out[base + 2] = by1[idx];
        out[base + 3] = bx2[idx];
        out[base + 4] = by2[idx];
    }
}

extern "C" void kernel_launch(void* const* d_in, const int* in_sizes, int n_in,
                              void* d_out, int out_size, void* d_ws, size_t ws_size,
                              hipStream_t stream) {
    const float* loc   = (const float*)d_in[0];
    const float* conf  = (const float*)d_in[1];
    const float* prior = (const float*)d_in[2];
    float* out = (float*)d_out;
    char* ws = (char*)d_ws;

    // ws layout (bytes): hist 2097152 | counts 128 | tbin 128 | keys 524288 | sscore 192000 | sbox 768000
    u32* hist    = (u32*)(ws + 0);
    u32* counts  = (u32*)(ws + 2097152);
    int* tbin    = (int*)(ws + 2097280);
    u64* keys    = (u64*)(ws + 2097408);
    float* sscore = (float*)(ws + 2621696);
    float* sbox   = (float*)(ws + 2813696);

    // zero hist+counts (524288+32 u32 words) and the whole output (480000 f32)
    zero_kernel<<<2048, 256, 0, stream>>>(hist, 524320, (u32*)out, 480000);
    hist_kernel<<<dim3(300, 32), 256, 0, stream>>>(conf, hist);
    thresh_kernel<<<32, 256, 0, stream>>>(hist, tbin);
    compact_kernel<<<dim3(300, 32), 256, 0, stream>>>(conf, tbin, counts, keys);
    sort_decode_kernel<<<32, 256, 0, stream>>>(keys, counts, loc, prior, sscore, sbox);
    nms_kernel<<<32, 256, 0, stream>>>(sscore, sbox, out);
}

// Round 2
// 702.561 us; speedup vs baseline: 1.3333x; 1.3333x over previous
//
#include <hip/hip_runtime.h>
#include <stdint.h>

typedef unsigned long long u64;
typedef unsigned int u32;

#define NUM_B 32
#define NUM_P 76800
#define TOPK 1500
#define NBINS 16384
#define CAP 2048
#define NWORDS 24  // ceil(1536/64) bit-words for active mask

__device__ __forceinline__ u32 fbits(float f) { return __float_as_uint(f); }

// ---------------- zero out + histogram scratch ----------------
__global__ void zero_kernel(u32* a, int n, u32* b, int nb) {
    int i = blockIdx.x * blockDim.x + threadIdx.x;
    int stride = gridDim.x * blockDim.x;
    for (int t = i; t < n; t += stride) a[t] = 0;
    for (int t = i; t < nb; t += stride) b[t] = 0;
}

// ---------------- histogram of class-1 score bits (top 16 bits) ----------------
__global__ void hist_kernel(const float* __restrict__ conf, u32* __restrict__ hist) {
    int p = blockIdx.x * blockDim.x + threadIdx.x;
    int b = blockIdx.y;
    if (p >= NUM_P) return;
    float s = conf[((size_t)b * NUM_P + p) * 2 + 1];
    if (s > 0.01f) {
        u32 bin = fbits(s) >> 16;   // s in (0.01,1) -> bin < 16384
        if (bin >= NBINS) bin = NBINS - 1;
        atomicAdd(&hist[(size_t)b * NBINS + bin], 1u);
    }
}

// ---------------- find per-batch threshold bin: smallest bin T with suffix count >= TOPK ----
__global__ void thresh_kernel(const u32* __restrict__ hist, int* __restrict__ tbin) {
    int b = blockIdx.x;
    int tid = threadIdx.x;
    __shared__ u32 vals[256];
    __shared__ int s_min;
    u32 total = 0;
    for (int c = 0; c < NBINS / 256; ++c) {
        if (tid == 0) s_min = 256;
        int bin = NBINS - 1 - (c * 256 + tid);
        u32 v = hist[(size_t)b * NBINS + bin];
        __syncthreads();        // covers s_min reset + previous-iter vals reads
        vals[tid] = v;
        __syncthreads();
        // inclusive Hillis-Steele scan over tid (suffix over bins)
        for (int off = 1; off < 256; off <<= 1) {
            u32 add = (tid >= off) ? vals[tid - off] : 0;
            __syncthreads();
            vals[tid] += add;
            __syncthreads();
        }
        u32 cum = total + vals[tid];
        if (cum >= TOPK) atomicMin(&s_min, tid);
        __syncthreads();
        if (s_min < 256) {
            if (tid == 0) tbin[b] = NBINS - 1 - (c * 256 + s_min);
            return;
        }
        total += vals[255];
    }
    if (tid == 0) tbin[b] = 0;  // fewer than TOPK candidates
}

// ---------------- compact candidate keys (score_bits<<32 | ~index) ----------------
// Per-block aggregation: 1 global atomicAdd per block instead of per thread
// (R1 fix: per-thread atomics on 32 shared counters serialized -> 321 us).
__global__ __launch_bounds__(256) void compact_kernel(
    const float* __restrict__ conf, const int* __restrict__ tbin,
    u32* __restrict__ counts, u64* __restrict__ keys) {
    int p = blockIdx.x * blockDim.x + threadIdx.x;
    int b = blockIdx.y;
    int tid = threadIdx.x;
    int wave = tid >> 6, lane = tid & 63;

    bool v = false;
    float s = 0.f;
    if (p < NUM_P) {
        s = conf[((size_t)b * NUM_P + p) * 2 + 1];
        if (s > 0.01f) {
            u32 bin = fbits(s) >> 16;
            if (bin >= NBINS) bin = NBINS - 1;
            v = ((int)bin >= tbin[b]);
        }
    }

    u64 mask = __ballot(v);
    u32 lane_prefix = (u32)__popcll(mask & ((lane == 63) ? ~0ULL >> 1 : ((1ULL << ((lane & 63) + (lane != 63 ? 0 : 0))) - 1ULL)));
    // simpler & correct: bits strictly below this lane
    lane_prefix = (u32)__popcll(mask & ((1ULL << lane) - 1ULL));
    u32 wave_cnt = (u32)__popcll(mask);

    __shared__ u32 wcnt[4];
    __shared__ u32 s_base;
    if (lane == 0) wcnt[wave] = wave_cnt;
    __syncthreads();
    if (tid == 0) {
        u32 tot = wcnt[0] + wcnt[1] + wcnt[2] + wcnt[3];
        s_base = (tot > 0) ? atomicAdd(&counts[b], tot) : 0u;
    }
    __syncthreads();
    if (v) {
        u32 woff = 0;
        for (int w = 0; w < wave; ++w) woff += wcnt[w];
        u32 pos = s_base + woff + lane_prefix;
        if (pos < CAP) keys[(size_t)b * CAP + pos] = ((u64)fbits(s) << 32) | (u32)(~p);
    }
}

// ---------------- bitonic sort 2048 keys desc, take top-1500, gather+decode boxes ----------
__global__ __launch_bounds__(256) void sort_decode_kernel(
    const u64* __restrict__ keys, const u32* __restrict__ counts,
    const float* __restrict__ loc, const float* __restrict__ prior,
    float* __restrict__ sscore, float* __restrict__ sbox) {
#pragma clang fp contract(off)
    int b = blockIdx.x, tid = threadIdx.x;
    __shared__ u64 k[CAP];
    int n = (int)min(counts[b], (u32)CAP);
    for (int t = tid; t < CAP; t += 256)
        k[t] = (t < n) ? keys[(size_t)b * CAP + t] : 0ULL;
    __syncthreads();
    for (int kk = 2; kk <= CAP; kk <<= 1) {
        for (int j = kk >> 1; j > 0; j >>= 1) {
            for (int t = tid; t < CAP; t += 256) {
                int l = t ^ j;
                if (l > t) {
                    u64 a = k[t], c = k[l];
                    bool desc = ((t & kk) == 0);
                    if (desc ? (a < c) : (a > c)) { k[t] = c; k[l] = a; }
                }
            }
            __syncthreads();
        }
    }
    for (int r = tid; r < TOPK; r += 256) {
        u64 key = k[r];
        float sc = 0.f, x1 = 0.f, y1 = 0.f, x2 = 0.f, y2 = 0.f;
        if (key != 0ULL) {
            u32 pidx = ~(u32)key;
            sc = __uint_as_float((u32)(key >> 32));
            const float* lp = &loc[((size_t)b * NUM_P + pidx) * 4];
            const float* pp = &prior[(size_t)pidx * 4];
            float lx = lp[0], ly = lp[1], lw = lp[2], lh = lp[3];
            float pcx = pp[0], pcy = pp[1], pw = pp[2], ph = pp[3];
            float cx = pcx + (lx * 0.1f) * pw;   // match np: (loc*VAR0)*prior_wh + prior_cxcy
            float cy = pcy + (ly * 0.1f) * ph;
            float w  = pw * expf(lw * 0.2f);
            float h  = ph * expf(lh * 0.2f);
            x1 = cx - w * 0.5f;
            y1 = cy - h * 0.5f;
            x2 = x1 + w;
            y2 = y1 + h;
        }
        sscore[(size_t)b * TOPK + r] = sc;
        float* bx = &sbox[((size_t)b * TOPK + r) * 4];
        bx[0] = x1; bx[1] = y1; bx[2] = x2; bx[3] = y2;
    }
}

// ---------------- greedy NMS (one block per batch) + compacted output write ----------------
__global__ __launch_bounds__(256) void nms_kernel(
    const float* __restrict__ sscore, const float* __restrict__ sbox,
    float* __restrict__ out) {
#pragma clang fp contract(off)
    int b = blockIdx.x, tid = threadIdx.x;
    __shared__ float bx1[TOPK], by1[TOPK], bx2[TOPK], by2[TOPK], bar[TOPK], bsc[TOPK];
    __shared__ u64 act[NWORDS];
    __shared__ int s_next;
    __shared__ short keep_list[TOPK];

    for (int r = tid; r < TOPK; r += 256) {
        float sc = sscore[(size_t)b * TOPK + r];
        const float* bp = &sbox[((size_t)b * TOPK + r) * 4];
        float x1 = bp[0], y1 = bp[1], x2 = bp[2], y2 = bp[3];
        bx1[r] = x1; by1[r] = y1; bx2[r] = x2; by2[r] = y2;
        bar[r] = (x2 - x1) * (y2 - y1);
        bsc[r] = sc;
    }
    if (tid < NWORDS) act[tid] = 0ULL;
    __syncthreads();
    // build active bitmask via wave ballots (valid = real candidate, score>0)
    for (int c = 0; c < 6; ++c) {
        int r = c * 256 + tid;
        bool v = (r < TOPK) && (bsc[r] > 0.0f);
        u64 m = __ballot(v);
        if ((tid & 63) == 0) act[c * 4 + (tid >> 6)] = m;
    }
    __syncthreads();

    int i = 0;
    int kcnt = 0;
    while (true) {
        if (tid == 0) {
            int w = i >> 6;
            int found = TOPK;
            u64 word = act[w] & (~0ULL << (i & 63));
            while (true) {
                if (word) { found = (w << 6) + __ffsll(word) - 1; break; }
                ++w;
                if (w >= NWORDS) break;
                word = act[w];
            }
            s_next = found;
        }
        __syncthreads();
        i = s_next;
        if (i >= TOPK) break;
        if (tid == 0) keep_list[kcnt] = (short)i;
        kcnt++;
        float x1i = bx1[i], y1i = by1[i], x2i = bx2[i], y2i = by2[i], ai = bar[i];
        for (int r = i + 1 + tid; r < TOPK; r += 256) {
            int w = r >> 6;
            u64 bit = 1ULL << (r & 63);
            if (act[w] & bit) {
                float xx1 = fmaxf(bx1[r], x1i);
                float yy1 = fmaxf(by1[r], y1i);
                float xx2 = fminf(bx2[r], x2i);
                float yy2 = fminf(by2[r], y2i);
                float iw = fmaxf(xx2 - xx1, 0.0f);
                float ih = fmaxf(yy2 - yy1, 0.0f);
                float inter = iw * ih;
                float denom = (bar[r] + ai) - inter;
                float iou = inter / denom;
                if (iou > 0.2f) atomicAnd(&act[w], ~bit);
            }
        }
        i = i + 1;
        __syncthreads();
    }
    // kept rows -> out[b][1][r][0..4]; everything else already zeroed
    for (int r = tid; r < kcnt; r += 256) {
        int idx = keep_list[r];
        size_t base = (((size_t)b * 2 + 1) * TOPK + (size_t)r) * 5;
        out[base + 0] = bsc[idx];
        out[base + 1] = bx1[idx];
        out[base + 2] = by1[idx];
        out[base + 3] = bx2[idx];
        out[base + 4] = by2[idx];
    }
}

extern "C" void kernel_launch(void* const* d_in, const int* in_sizes, int n_in,
                              void* d_out, int out_size, void* d_ws, size_t ws_size,
                              hipStream_t stream) {
    const float* loc   = (const float*)d_in[0];
    const float* conf  = (const float*)d_in[1];
    const float* prior = (const float*)d_in[2];
    float* out = (float*)d_out;
    char* ws = (char*)d_ws;

    // ws layout (bytes): hist 2097152 | counts 128 | tbin 128 | keys 524288 | sscore 192000 | sbox 768000
    u32* hist    = (u32*)(ws + 0);
    u32* counts  = (u32*)(ws + 2097152);
    int* tbin    = (int*)(ws + 2097280);
    u64* keys    = (u64*)(ws + 2097408);
    float* sscore = (float*)(ws + 2621696);
    float* sbox   = (float*)(ws + 2813696);

    // zero hist+counts (524288+32 u32 words) and the whole output (480000 f32)
    zero_kernel<<<2048, 256, 0, stream>>>(hist, 524320, (u32*)out, 480000);
    hist_kernel<<<dim3(300, 32), 256, 0, stream>>>(conf, hist);
    thresh_kernel<<<32, 256, 0, stream>>>(hist, tbin);
    compact_kernel<<<dim3(300, 32), 256, 0, stream>>>(conf, tbin, counts, keys);
    sort_decode_kernel<<<32, 256, 0, stream>>>(keys, counts, loc, prior, sscore, sbox);
    nms_kernel<<<32, 256, 0, stream>>>(sscore, sbox, out);
}

// Round 3
// 681.199 us; speedup vs baseline: 1.3751x; 1.0314x over previous
//
#include <hip/hip_runtime.h>
#include <stdint.h>

typedef unsigned long long u64;
typedef unsigned int u32;

#define NUM_B 32
#define NUM_P 76800
#define TOPK 1500
#define NBINS 16384
#define CAP 2048
#define NWORDS 24  // ceil(1500/64) u64 words per mask row
#define PF 16      // sweep prefetch depth (divides 64)

__device__ __forceinline__ u32 fbits(float f) { return __float_as_uint(f); }

// ---------------- zero out + scratch ----------------
__global__ void zero_kernel(u32* a, int n, u32* b, int nb, u32* c, int nc) {
    int i = blockIdx.x * blockDim.x + threadIdx.x;
    int stride = gridDim.x * blockDim.x;
    for (int t = i; t < n; t += stride) a[t] = 0;
    for (int t = i; t < nb; t += stride) b[t] = 0;
    for (int t = i; t < nc; t += stride) c[t] = 0;
}

// ---------------- histogram of class-1 score bits (top 16 bits) ----------------
__global__ void hist_kernel(const float* __restrict__ conf, u32* __restrict__ hist) {
    int p = blockIdx.x * blockDim.x + threadIdx.x;
    int b = blockIdx.y;
    if (p >= NUM_P) return;
    float s = conf[((size_t)b * NUM_P + p) * 2 + 1];
    if (s > 0.01f) {
        u32 bin = fbits(s) >> 16;   // s in (0.01,1) -> bin < 16384
        if (bin >= NBINS) bin = NBINS - 1;
        atomicAdd(&hist[(size_t)b * NBINS + bin], 1u);
    }
}

// ---------------- find per-batch threshold bin: smallest bin T with suffix count >= TOPK ----
__global__ void thresh_kernel(const u32* __restrict__ hist, int* __restrict__ tbin) {
    int b = blockIdx.x;
    int tid = threadIdx.x;
    __shared__ u32 vals[256];
    __shared__ int s_min;
    u32 total = 0;
    for (int c = 0; c < NBINS / 256; ++c) {
        if (tid == 0) s_min = 256;
        int bin = NBINS - 1 - (c * 256 + tid);
        u32 v = hist[(size_t)b * NBINS + bin];
        __syncthreads();
        vals[tid] = v;
        __syncthreads();
        for (int off = 1; off < 256; off <<= 1) {
            u32 add = (tid >= off) ? vals[tid - off] : 0;
            __syncthreads();
            vals[tid] += add;
            __syncthreads();
        }
        u32 cum = total + vals[tid];
        if (cum >= TOPK) atomicMin(&s_min, tid);
        __syncthreads();
        if (s_min < 256) {
            if (tid == 0) tbin[b] = NBINS - 1 - (c * 256 + s_min);
            return;
        }
        total += vals[255];
    }
    if (tid == 0) tbin[b] = 0;
}

// ---------------- compact candidate keys (score_bits<<32 | ~index), 1 atomic/block ----------
__global__ __launch_bounds__(256) void compact_kernel(
    const float* __restrict__ conf, const int* __restrict__ tbin,
    u32* __restrict__ counts, u64* __restrict__ keys) {
    int p = blockIdx.x * blockDim.x + threadIdx.x;
    int b = blockIdx.y;
    int tid = threadIdx.x;
    int wave = tid >> 6, lane = tid & 63;

    bool v = false;
    float s = 0.f;
    if (p < NUM_P) {
        s = conf[((size_t)b * NUM_P + p) * 2 + 1];
        if (s > 0.01f) {
            u32 bin = fbits(s) >> 16;
            if (bin >= NBINS) bin = NBINS - 1;
            v = ((int)bin >= tbin[b]);
        }
    }

    u64 mask = __ballot(v);
    u32 lane_prefix = (u32)__popcll(mask & ((1ULL << lane) - 1ULL));
    u32 wave_cnt = (u32)__popcll(mask);

    __shared__ u32 wcnt[4];
    __shared__ u32 s_base;
    if (lane == 0) wcnt[wave] = wave_cnt;
    __syncthreads();
    if (tid == 0) {
        u32 tot = wcnt[0] + wcnt[1] + wcnt[2] + wcnt[3];
        s_base = (tot > 0) ? atomicAdd(&counts[b], tot) : 0u;
    }
    __syncthreads();
    if (v) {
        u32 woff = 0;
        for (int w = 0; w < wave; ++w) woff += wcnt[w];
        u32 pos = s_base + woff + lane_prefix;
        if (pos < CAP) keys[(size_t)b * CAP + pos] = ((u64)fbits(s) << 32) | (u32)(~p);
    }
}

// ---------------- bitonic sort 2048 keys desc, take top-1500, gather+decode boxes ----------
__global__ __launch_bounds__(256) void sort_decode_kernel(
    const u64* __restrict__ keys, const u32* __restrict__ counts,
    const float* __restrict__ loc, const float* __restrict__ prior,
    float* __restrict__ sscore, float* __restrict__ sbox) {
#pragma clang fp contract(off)
    int b = blockIdx.x, tid = threadIdx.x;
    __shared__ u64 k[CAP];
    int n = (int)min(counts[b], (u32)CAP);
    for (int t = tid; t < CAP; t += 256)
        k[t] = (t < n) ? keys[(size_t)b * CAP + t] : 0ULL;
    __syncthreads();
    for (int kk = 2; kk <= CAP; kk <<= 1) {
        for (int j = kk >> 1; j > 0; j >>= 1) {
            for (int t = tid; t < CAP; t += 256) {
                int l = t ^ j;
                if (l > t) {
                    u64 a = k[t], c = k[l];
                    bool desc = ((t & kk) == 0);
                    if (desc ? (a < c) : (a > c)) { k[t] = c; k[l] = a; }
                }
            }
            __syncthreads();
        }
    }
    for (int r = tid; r < TOPK; r += 256) {
        u64 key = k[r];
        float sc = 0.f, x1 = 0.f, y1 = 0.f, x2 = 0.f, y2 = 0.f;
        if (key != 0ULL) {
            u32 pidx = ~(u32)key;
            sc = __uint_as_float((u32)(key >> 32));
            const float* lp = &loc[((size_t)b * NUM_P + pidx) * 4];
            const float* pp = &prior[(size_t)pidx * 4];
            float lx = lp[0], ly = lp[1], lw = lp[2], lh = lp[3];
            float pcx = pp[0], pcy = pp[1], pw = pp[2], ph = pp[3];
            float cx = pcx + (lx * 0.1f) * pw;
            float cy = pcy + (ly * 0.1f) * ph;
            float w  = pw * expf(lw * 0.2f);
            float h  = ph * expf(lh * 0.2f);
            x1 = cx - w * 0.5f;
            y1 = cy - h * 0.5f;
            x2 = x1 + w;
            y2 = y1 + h;
        }
        sscore[(size_t)b * TOPK + r] = sc;
        float* bx = &sbox[((size_t)b * TOPK + r) * 4];
        bx[0] = x1; bx[1] = y1; bx[2] = x2; bx[3] = y2;
    }
}

// ---------------- NMS phase 1: suppression bitmask, fully parallel ----------------
// block (w, b): word w's 64 column-boxes staged in LDS; threads sweep rows.
// mask[b][i][w] bit j2 set iff j = w*64+j2 > i and IoU(i,j) > 0.2.
__global__ __launch_bounds__(256) void mask_kernel(
    const float* __restrict__ sbox, u64* __restrict__ mask) {
#pragma clang fp contract(off)
    int w = blockIdx.x, b = blockIdx.y, tid = threadIdx.x;
    __shared__ float cx1[64], cy1[64], cx2[64], cy2[64], car[64];
    if (tid < 64) {
        int j = w * 64 + tid;
        float x1 = 0.f, y1 = 0.f, x2 = 0.f, y2 = 0.f;
        if (j < TOPK) {
            const float4 bx = ((const float4*)sbox)[(size_t)b * TOPK + j];
            x1 = bx.x; y1 = bx.y; x2 = bx.z; y2 = bx.w;
        }
        cx1[tid] = x1; cy1[tid] = y1; cx2[tid] = x2; cy2[tid] = y2;
        car[tid] = (x2 - x1) * (y2 - y1);
    }
    __syncthreads();
    for (int i = tid; i < TOPK; i += 256) {
        u64 m = 0;
        if (w * 64 + 63 > i) {  // word has at least one j > i
            const float4 bx = ((const float4*)sbox)[(size_t)b * TOPK + i];
            float x1i = bx.x, y1i = bx.y, x2i = bx.z, y2i = bx.w;
            float ai = (x2i - x1i) * (y2i - y1i);
            for (int j2 = 0; j2 < 64; ++j2) {
                int j = w * 64 + j2;
                float xx1 = fmaxf(cx1[j2], x1i);
                float yy1 = fmaxf(cy1[j2], y1i);
                float xx2 = fminf(cx2[j2], x2i);
                float yy2 = fminf(cy2[j2], y2i);
                float iw = fmaxf(xx2 - xx1, 0.0f);
                float ih = fmaxf(yy2 - yy1, 0.0f);
                float inter = iw * ih;
                float iou = inter / ((car[j2] + ai) - inter);
                if ((iou > 0.2f) && (j > i)) m |= (1ULL << j2);
            }
        }
        mask[((size_t)b * TOPK + i) * NWORDS + w] = m;
    }
}

// ---------------- NMS phase 2: serial sweep, one wave per batch ----------------
// active bitmap: 1 u64/lane (lanes 0..23). mask rows register-prefetched PF deep.
// Since mask only has j>i bits, final active bitmap == keep set.
__global__ __launch_bounds__(64) void sweep_kernel(
    const u64* __restrict__ mask, const float* __restrict__ sscore,
    const float* __restrict__ sbox, float* __restrict__ out) {
    int b = blockIdx.x, lane = threadIdx.x;

    // build initial active mask from validity (score > 0)
    u64 act = 0;
    for (int c = 0; c < NWORDS; ++c) {
        int r = c * 64 + lane;
        bool v = (r < TOPK) && (sscore[(size_t)b * TOPK + r] > 0.0f);
        u64 m = __ballot(v);
        if (lane == c) act = m;
    }

    // prefetch ring
    u64 buf[PF];
#pragma unroll
    for (int t = 0; t < PF; ++t)
        buf[t] = (lane < NWORDS) ? mask[((size_t)b * TOPK + t) * NWORDS + lane] : 0ULL;

    u64 cur = __shfl(act, 0);   // current word's live copy (broadcast)
    for (int base = 0; base < TOPK; base += PF) {
#pragma unroll
        for (int t = 0; t < PF; ++t) {
            int i = base + t;
            u64 row = buf[t];
            int nxt = i + PF;
            buf[t] = (lane < NWORDS && nxt < TOPK)
                         ? mask[((size_t)b * TOPK + nxt) * NWORDS + lane] : 0ULL;
            if ((i & 63) == 0) cur = __shfl(act, i >> 6);  // refresh at word entry
            u64 srow = __shfl(row, i >> 6);                // off-chain, issues early
            if ((cur >> (i & 63)) & 1ULL) {                // kept (wave-uniform)
                act &= ~row;
                cur &= ~srow;
            }
        }
    }

    // epilogue: act == keep bitmap; rank by prefix popcount, write compacted rows
    __shared__ u64 aw[NWORDS];
    __shared__ u32 pfx[NWORDS + 1];
    if (lane < NWORDS) aw[lane] = act;
    __syncthreads();
    if (lane == 0) {
        u32 acc = 0;
        for (int wd = 0; wd < NWORDS; ++wd) { pfx[wd] = acc; acc += (u32)__popcll(aw[wd]); }
        pfx[NWORDS] = acc;
    }
    __syncthreads();
    for (int r = lane; r < TOPK; r += 64) {
        int wd = r >> 6;
        u64 word = aw[wd];
        if ((word >> (r & 63)) & 1ULL) {
            u32 rank = pfx[wd] + (u32)__popcll(word & ((1ULL << (r & 63)) - 1ULL));
            float sc = sscore[(size_t)b * TOPK + r];
            float4 bx = ((const float4*)sbox)[(size_t)b * TOPK + r];
            size_t base_o = (((size_t)b * 2 + 1) * TOPK + (size_t)rank) * 5;
            out[base_o + 0] = sc;
            out[base_o + 1] = bx.x;
            out[base_o + 2] = bx.y;
            out[base_o + 3] = bx.z;
            out[base_o + 4] = bx.w;
        }
    }
}

extern "C" void kernel_launch(void* const* d_in, const int* in_sizes, int n_in,
                              void* d_out, int out_size, void* d_ws, size_t ws_size,
                              hipStream_t stream) {
    const float* loc   = (const float*)d_in[0];
    const float* conf  = (const float*)d_in[1];
    const float* prior = (const float*)d_in[2];
    float* out = (float*)d_out;
    char* ws = (char*)d_ws;

    // ws layout (bytes):
    //   mask   0        .. 9216000   (32*1500*24*8) — hist aliases its first 2 MB
    //   counts 9216000  (+128)
    //   tbin   9216128  (+128)
    //   keys   9216256  (+524288)
    //   sscore 9740544  (+192000)
    //   sbox   9932544  (+768000)  -> total 10,700,544 B
    u64* mask_buf = (u64*)(ws + 0);
    u32* hist     = (u32*)(ws + 0);            // dead after thresh_kernel
    u32* counts   = (u32*)(ws + 9216000);
    int* tbin     = (int*)(ws + 9216128);
    u64* keys     = (u64*)(ws + 9216256);
    float* sscore = (float*)(ws + 9740544);
    float* sbox   = (float*)(ws + 9932544);

    zero_kernel<<<2048, 256, 0, stream>>>(hist, NBINS * NUM_B, counts, NUM_B,
                                          (u32*)out, 480000);
    hist_kernel<<<dim3(300, 32), 256, 0, stream>>>(conf, hist);
    thresh_kernel<<<32, 256, 0, stream>>>(hist, tbin);
    compact_kernel<<<dim3(300, 32), 256, 0, stream>>>(conf, tbin, counts, keys);
    sort_decode_kernel<<<32, 256, 0, stream>>>(keys, counts, loc, prior, sscore, sbox);
    mask_kernel<<<dim3(NWORDS, 32), 256, 0, stream>>>(sbox, mask_buf);
    sweep_kernel<<<32, 64, 0, stream>>>(mask_buf, sscore, sbox, out);
}

// Round 4
// 565.277 us; speedup vs baseline: 1.6571x; 1.2051x over previous
//
#include <hip/hip_runtime.h>
#include <stdint.h>

typedef unsigned long long u64;
typedef unsigned int u32;

#define NUM_B 32
#define NUM_P 76800
#define TOPK 1500
#define NBINS 4096   // linear bins: bin = min(int(s*4096), 4095); uniform occupancy
#define CAP 2048
#define NWORDS 24    // ceil(1500/64) u64 words per mask row
#define PF 16        // sweep prefetch depth (divides 64)

__device__ __forceinline__ u32 fbits(float f) { return __float_as_uint(f); }
// Monotone non-decreasing in s => threshold-bin selection is order-correct.
__device__ __forceinline__ int binOf(float s) {
    int b = (int)(s * (float)NBINS);
    return (b > NBINS - 1) ? NBINS - 1 : b;
}

// ---------------- zero out + scratch ----------------
__global__ void zero_kernel(u32* a, int n, u32* b, int nb, u32* c, int nc) {
    int i = blockIdx.x * blockDim.x + threadIdx.x;
    int stride = gridDim.x * blockDim.x;
    for (int t = i; t < n; t += stride) a[t] = 0;
    for (int t = i; t < nb; t += stride) b[t] = 0;
    for (int t = i; t < nc; t += stride) c[t] = 0;
}

// ---------------- linear histogram of class-1 scores ----------------
__global__ void hist_kernel(const float* __restrict__ conf, u32* __restrict__ hist) {
    int p = blockIdx.x * blockDim.x + threadIdx.x;
    int b = blockIdx.y;
    if (p >= NUM_P) return;
    float s = conf[((size_t)b * NUM_P + p) * 2 + 1];
    if (s > 0.01f) {
        atomicAdd(&hist[(size_t)b * NBINS + binOf(s)], 1u);
    }
}

// ---------------- find per-batch threshold bin: smallest bin T with suffix count >= TOPK ----
__global__ void thresh_kernel(const u32* __restrict__ hist, int* __restrict__ tbin) {
    int b = blockIdx.x;
    int tid = threadIdx.x;
    __shared__ u32 vals[256];
    __shared__ int s_min;
    u32 total = 0;
    for (int c = 0; c < NBINS / 256; ++c) {
        if (tid == 0) s_min = 256;
        int bin = NBINS - 1 - (c * 256 + tid);
        u32 v = hist[(size_t)b * NBINS + bin];
        __syncthreads();
        vals[tid] = v;
        __syncthreads();
        for (int off = 1; off < 256; off <<= 1) {
            u32 add = (tid >= off) ? vals[tid - off] : 0;
            __syncthreads();
            vals[tid] += add;
            __syncthreads();
        }
        u32 cum = total + vals[tid];
        if (cum >= TOPK) atomicMin(&s_min, tid);
        __syncthreads();
        if (s_min < 256) {
            if (tid == 0) tbin[b] = NBINS - 1 - (c * 256 + s_min);
            return;
        }
        total += vals[255];
    }
    if (tid == 0) tbin[b] = 0;
}

// ---------------- compact candidate keys (score_bits<<32 | ~index), 1 atomic/block ----------
__global__ __launch_bounds__(256) void compact_kernel(
    const float* __restrict__ conf, const int* __restrict__ tbin,
    u32* __restrict__ counts, u64* __restrict__ keys) {
    int p = blockIdx.x * blockDim.x + threadIdx.x;
    int b = blockIdx.y;
    int tid = threadIdx.x;
    int wave = tid >> 6, lane = tid & 63;

    bool v = false;
    float s = 0.f;
    if (p < NUM_P) {
        s = conf[((size_t)b * NUM_P + p) * 2 + 1];
        if (s > 0.01f) v = (binOf(s) >= tbin[b]);
    }

    u64 mask = __ballot(v);
    u32 lane_prefix = (u32)__popcll(mask & ((1ULL << lane) - 1ULL));
    u32 wave_cnt = (u32)__popcll(mask);

    __shared__ u32 wcnt[4];
    __shared__ u32 s_base;
    if (lane == 0) wcnt[wave] = wave_cnt;
    __syncthreads();
    if (tid == 0) {
        u32 tot = wcnt[0] + wcnt[1] + wcnt[2] + wcnt[3];
        s_base = (tot > 0) ? atomicAdd(&counts[b], tot) : 0u;
    }
    __syncthreads();
    if (v) {
        u32 woff = 0;
        for (int w = 0; w < wave; ++w) woff += wcnt[w];
        u32 pos = s_base + woff + lane_prefix;
        if (pos < CAP) keys[(size_t)b * CAP + pos] = ((u64)fbits(s) << 32) | (u32)(~p);
    }
}

// ---------------- bitonic sort 2048 keys desc, take top-1500, gather+decode boxes ----------
__global__ __launch_bounds__(256) void sort_decode_kernel(
    const u64* __restrict__ keys, const u32* __restrict__ counts,
    const float* __restrict__ loc, const float* __restrict__ prior,
    float* __restrict__ sscore, float* __restrict__ sbox) {
#pragma clang fp contract(off)
    int b = blockIdx.x, tid = threadIdx.x;
    __shared__ u64 k[CAP];
    int n = (int)min(counts[b], (u32)CAP);
    for (int t = tid; t < CAP; t += 256)
        k[t] = (t < n) ? keys[(size_t)b * CAP + t] : 0ULL;
    __syncthreads();
    for (int kk = 2; kk <= CAP; kk <<= 1) {
        for (int j = kk >> 1; j > 0; j >>= 1) {
            for (int t = tid; t < CAP; t += 256) {
                int l = t ^ j;
                if (l > t) {
                    u64 a = k[t], c = k[l];
                    bool desc = ((t & kk) == 0);
                    if (desc ? (a < c) : (a > c)) { k[t] = c; k[l] = a; }
                }
            }
            __syncthreads();
        }
    }
    for (int r = tid; r < TOPK; r += 256) {
        u64 key = k[r];
        float sc = 0.f, x1 = 0.f, y1 = 0.f, x2 = 0.f, y2 = 0.f;
        if (key != 0ULL) {
            u32 pidx = ~(u32)key;
            sc = __uint_as_float((u32)(key >> 32));
            const float* lp = &loc[((size_t)b * NUM_P + pidx) * 4];
            const float* pp = &prior[(size_t)pidx * 4];
            float lx = lp[0], ly = lp[1], lw = lp[2], lh = lp[3];
            float pcx = pp[0], pcy = pp[1], pw = pp[2], ph = pp[3];
            float cx = pcx + (lx * 0.1f) * pw;
            float cy = pcy + (ly * 0.1f) * ph;
            float w  = pw * expf(lw * 0.2f);
            float h  = ph * expf(lh * 0.2f);
            x1 = cx - w * 0.5f;
            y1 = cy - h * 0.5f;
            x2 = x1 + w;
            y2 = y1 + h;
        }
        sscore[(size_t)b * TOPK + r] = sc;
        float* bx = &sbox[((size_t)b * TOPK + r) * 4];
        bx[0] = x1; bx[1] = y1; bx[2] = x2; bx[3] = y2;
    }
}

// ---------------- NMS phase 1: suppression bitmask, fully parallel ----------------
// block (w, b): word w's 64 column-boxes staged in LDS (float4 + area);
// threads sweep rows. mask[b][i][w] bit j2 set iff j = w*64+j2 > i and IoU > 0.2.
__global__ __launch_bounds__(256) void mask_kernel(
    const float* __restrict__ sbox, u64* __restrict__ mask) {
#pragma clang fp contract(off)
    int w = blockIdx.x, b = blockIdx.y, tid = threadIdx.x;
    __shared__ float4 cbox[64];
    __shared__ float car[64];
    if (tid < 64) {
        int j = w * 64 + tid;
        float4 bx = make_float4(0.f, 0.f, 0.f, 0.f);
        if (j < TOPK) bx = ((const float4*)sbox)[(size_t)b * TOPK + j];
        cbox[tid] = bx;
        car[tid] = (bx.z - bx.x) * (bx.w - bx.y);
    }
    __syncthreads();
    for (int i = tid; i < TOPK; i += 256) {
        u64 m = 0;
        if (w * 64 + 63 > i) {  // word has at least one j > i
            const float4 bx = ((const float4*)sbox)[(size_t)b * TOPK + i];
            float x1i = bx.x, y1i = bx.y, x2i = bx.z, y2i = bx.w;
            float ai = (x2i - x1i) * (y2i - y1i);
            for (int j2 = 0; j2 < 64; ++j2) {
                int j = w * 64 + j2;
                float4 cb = cbox[j2];
                float xx1 = fmaxf(cb.x, x1i);
                float yy1 = fmaxf(cb.y, y1i);
                float xx2 = fminf(cb.z, x2i);
                float yy2 = fminf(cb.w, y2i);
                float iw = fmaxf(xx2 - xx1, 0.0f);
                float ih = fmaxf(yy2 - yy1, 0.0f);
                float inter = iw * ih;
                float iou = inter / ((car[j2] + ai) - inter);
                if ((iou > 0.2f) && (j > i)) m |= (1ULL << j2);
            }
        }
        mask[((size_t)b * TOPK + i) * NWORDS + w] = m;
    }
}

// ---------------- NMS phase 2: serial sweep, one wave per batch ----------------
__global__ __launch_bounds__(64) void sweep_kernel(
    const u64* __restrict__ mask, const float* __restrict__ sscore,
    const float* __restrict__ sbox, float* __restrict__ out) {
    int b = blockIdx.x, lane = threadIdx.x;

    u64 act = 0;
    for (int c = 0; c < NWORDS; ++c) {
        int r = c * 64 + lane;
        bool v = (r < TOPK) && (sscore[(size_t)b * TOPK + r] > 0.0f);
        u64 m = __ballot(v);
        if (lane == c) act = m;
    }

    u64 buf[PF];
#pragma unroll
    for (int t = 0; t < PF; ++t)
        buf[t] = (lane < NWORDS) ? mask[((size_t)b * TOPK + t) * NWORDS + lane] : 0ULL;

    u64 cur = __shfl(act, 0);
    for (int base = 0; base < TOPK; base += PF) {
#pragma unroll
        for (int t = 0; t < PF; ++t) {
            int i = base + t;
            u64 row = buf[t];
            int nxt = i + PF;
            buf[t] = (lane < NWORDS && nxt < TOPK)
                         ? mask[((size_t)b * TOPK + nxt) * NWORDS + lane] : 0ULL;
            if ((i & 63) == 0) cur = __shfl(act, i >> 6);
            u64 srow = __shfl(row, i >> 6);
            if ((cur >> (i & 63)) & 1ULL) {
                act &= ~row;
                cur &= ~srow;
            }
        }
    }

    __shared__ u64 aw[NWORDS];
    __shared__ u32 pfx[NWORDS + 1];
    if (lane < NWORDS) aw[lane] = act;
    __syncthreads();
    if (lane == 0) {
        u32 acc = 0;
        for (int wd = 0; wd < NWORDS; ++wd) { pfx[wd] = acc; acc += (u32)__popcll(aw[wd]); }
        pfx[NWORDS] = acc;
    }
    __syncthreads();
    for (int r = lane; r < TOPK; r += 64) {
        int wd = r >> 6;
        u64 word = aw[wd];
        if ((word >> (r & 63)) & 1ULL) {
            u32 rank = pfx[wd] + (u32)__popcll(word & ((1ULL << (r & 63)) - 1ULL));
            float sc = sscore[(size_t)b * TOPK + r];
            float4 bx = ((const float4*)sbox)[(size_t)b * TOPK + r];
            size_t base_o = (((size_t)b * 2 + 1) * TOPK + (size_t)rank) * 5;
            out[base_o + 0] = sc;
            out[base_o + 1] = bx.x;
            out[base_o + 2] = bx.y;
            out[base_o + 3] = bx.z;
            out[base_o + 4] = bx.w;
        }
    }
}

extern "C" void kernel_launch(void* const* d_in, const int* in_sizes, int n_in,
                              void* d_out, int out_size, void* d_ws, size_t ws_size,
                              hipStream_t stream) {
    const float* loc   = (const float*)d_in[0];
    const float* conf  = (const float*)d_in[1];
    const float* prior = (const float*)d_in[2];
    float* out = (float*)d_out;
    char* ws = (char*)d_ws;

    // ws layout (bytes):
    //   mask   0        .. 9216000   (32*1500*24*8) — hist (512KB) aliases its head
    //   counts 9216000  (+128)
    //   tbin   9216128  (+128)
    //   keys   9216256  (+524288)
    //   sscore 9740544  (+192000)
    //   sbox   9932544  (+768000)  -> total 10,700,544 B
    u64* mask_buf = (u64*)(ws + 0);
    u32* hist     = (u32*)(ws + 0);            // dead after thresh_kernel
    u32* counts   = (u32*)(ws + 9216000);
    int* tbin     = (int*)(ws + 9216128);
    u64* keys     = (u64*)(ws + 9216256);
    float* sscore = (float*)(ws + 9740544);
    float* sbox   = (float*)(ws + 9932544);

    zero_kernel<<<2048, 256, 0, stream>>>(hist, NBINS * NUM_B, counts, NUM_B,
                                          (u32*)out, 480000);
    hist_kernel<<<dim3(300, 32), 256, 0, stream>>>(conf, hist);
    thresh_kernel<<<32, 256, 0, stream>>>(hist, tbin);
    compact_kernel<<<dim3(300, 32), 256, 0, stream>>>(conf, tbin, counts, keys);
    sort_decode_kernel<<<32, 256, 0, stream>>>(keys, counts, loc, prior, sscore, sbox);
    mask_kernel<<<dim3(NWORDS, 32), 256, 0, stream>>>(sbox, mask_buf);
    sweep_kernel<<<32, 64, 0, stream>>>(mask_buf, sscore, sbox, out);
}

// Round 5
// 532.301 us; speedup vs baseline: 1.7598x; 1.0620x over previous
//
#include <hip/hip_runtime.h>
#include <stdint.h>

typedef unsigned long long u64;
typedef unsigned int u32;

#define NUM_B 32
#define NUM_P 76800
#define TOPK 1500
#define NBINS 4096   // linear bins: bin = min(int(s*4096), 4095); uniform occupancy
#define CAP 2048
#define NWORDS 24    // ceil(1500/64) u64 words per mask row
#define PF 32        // sweep prefetch depth

__device__ __forceinline__ u32 fbits(float f) { return __float_as_uint(f); }
// Monotone non-decreasing in s => threshold-bin selection is order-correct.
__device__ __forceinline__ int binOf(float s) {
    int b = (int)(s * (float)NBINS);
    return (b > NBINS - 1) ? NBINS - 1 : b;
}

// ---------------- zero out + scratch ----------------
__global__ void zero_kernel(u32* a, int n, u32* b, int nb, u32* c, int nc) {
    int i = blockIdx.x * blockDim.x + threadIdx.x;
    int stride = gridDim.x * blockDim.x;
    for (int t = i; t < n; t += stride) a[t] = 0;
    for (int t = i; t < nb; t += stride) b[t] = 0;
    for (int t = i; t < nc; t += stride) c[t] = 0;
}

// ---------------- linear histogram of class-1 scores ----------------
__global__ void hist_kernel(const float* __restrict__ conf, u32* __restrict__ hist) {
    int p = blockIdx.x * blockDim.x + threadIdx.x;
    int b = blockIdx.y;
    if (p >= NUM_P) return;
    float s = conf[((size_t)b * NUM_P + p) * 2 + 1];
    if (s > 0.01f) {
        atomicAdd(&hist[(size_t)b * NBINS + binOf(s)], 1u);
    }
}

// ---------------- find per-batch threshold bin: smallest bin T with suffix count >= TOPK ----
__global__ void thresh_kernel(const u32* __restrict__ hist, int* __restrict__ tbin) {
    int b = blockIdx.x;
    int tid = threadIdx.x;
    __shared__ u32 vals[256];
    __shared__ int s_min;
    u32 total = 0;
    for (int c = 0; c < NBINS / 256; ++c) {
        if (tid == 0) s_min = 256;
        int bin = NBINS - 1 - (c * 256 + tid);
        u32 v = hist[(size_t)b * NBINS + bin];
        __syncthreads();
        vals[tid] = v;
        __syncthreads();
        for (int off = 1; off < 256; off <<= 1) {
            u32 add = (tid >= off) ? vals[tid - off] : 0;
            __syncthreads();
            vals[tid] += add;
            __syncthreads();
        }
        u32 cum = total + vals[tid];
        if (cum >= TOPK) atomicMin(&s_min, tid);
        __syncthreads();
        if (s_min < 256) {
            if (tid == 0) tbin[b] = NBINS - 1 - (c * 256 + s_min);
            return;
        }
        total += vals[255];
    }
    if (tid == 0) tbin[b] = 0;
}

// ---------------- compact candidate keys (score_bits<<32 | ~index), 1 atomic/block ----------
__global__ __launch_bounds__(256) void compact_kernel(
    const float* __restrict__ conf, const int* __restrict__ tbin,
    u32* __restrict__ counts, u64* __restrict__ keys) {
    int p = blockIdx.x * blockDim.x + threadIdx.x;
    int b = blockIdx.y;
    int tid = threadIdx.x;
    int wave = tid >> 6, lane = tid & 63;

    bool v = false;
    float s = 0.f;
    if (p < NUM_P) {
        s = conf[((size_t)b * NUM_P + p) * 2 + 1];
        if (s > 0.01f) v = (binOf(s) >= tbin[b]);
    }

    u64 mask = __ballot(v);
    u32 lane_prefix = (u32)__popcll(mask & ((1ULL << lane) - 1ULL));
    u32 wave_cnt = (u32)__popcll(mask);

    __shared__ u32 wcnt[4];
    __shared__ u32 s_base;
    if (lane == 0) wcnt[wave] = wave_cnt;
    __syncthreads();
    if (tid == 0) {
        u32 tot = wcnt[0] + wcnt[1] + wcnt[2] + wcnt[3];
        s_base = (tot > 0) ? atomicAdd(&counts[b], tot) : 0u;
    }
    __syncthreads();
    if (v) {
        u32 woff = 0;
        for (int w = 0; w < wave; ++w) woff += wcnt[w];
        u32 pos = s_base + woff + lane_prefix;
        if (pos < CAP) keys[(size_t)b * CAP + pos] = ((u64)fbits(s) << 32) | (u32)(~p);
    }
}

// ---------------- bitonic sort 2048 keys desc, take top-1500, gather+decode boxes ----------
__global__ __launch_bounds__(256) void sort_decode_kernel(
    const u64* __restrict__ keys, const u32* __restrict__ counts,
    const float* __restrict__ loc, const float* __restrict__ prior,
    float* __restrict__ sscore, float* __restrict__ sbox) {
#pragma clang fp contract(off)
    int b = blockIdx.x, tid = threadIdx.x;
    __shared__ u64 k[CAP];
    int n = (int)min(counts[b], (u32)CAP);
    for (int t = tid; t < CAP; t += 256)
        k[t] = (t < n) ? keys[(size_t)b * CAP + t] : 0ULL;
    __syncthreads();
    for (int kk = 2; kk <= CAP; kk <<= 1) {
        for (int j = kk >> 1; j > 0; j >>= 1) {
            for (int t = tid; t < CAP; t += 256) {
                int l = t ^ j;
                if (l > t) {
                    u64 a = k[t], c = k[l];
                    bool desc = ((t & kk) == 0);
                    if (desc ? (a < c) : (a > c)) { k[t] = c; k[l] = a; }
                }
            }
            __syncthreads();
        }
    }
    for (int r = tid; r < TOPK; r += 256) {
        u64 key = k[r];
        float sc = 0.f, x1 = 0.f, y1 = 0.f, x2 = 0.f, y2 = 0.f;
        if (key != 0ULL) {
            u32 pidx = ~(u32)key;
            sc = __uint_as_float((u32)(key >> 32));
            const float* lp = &loc[((size_t)b * NUM_P + pidx) * 4];
            const float* pp = &prior[(size_t)pidx * 4];
            float lx = lp[0], ly = lp[1], lw = lp[2], lh = lp[3];
            float pcx = pp[0], pcy = pp[1], pw = pp[2], ph = pp[3];
            float cx = pcx + (lx * 0.1f) * pw;
            float cy = pcy + (ly * 0.1f) * ph;
            float w  = pw * expf(lw * 0.2f);
            float h  = ph * expf(lh * 0.2f);
            x1 = cx - w * 0.5f;
            y1 = cy - h * 0.5f;
            x2 = x1 + w;
            y2 = y1 + h;
        }
        sscore[(size_t)b * TOPK + r] = sc;
        float* bx = &sbox[((size_t)b * TOPK + r) * 4];
        bx[0] = x1; bx[1] = y1; bx[2] = x2; bx[3] = y2;
    }
}

// ---------------- NMS phase 1: suppression bitmask, fully parallel ----------------
__global__ __launch_bounds__(256) void mask_kernel(
    const float* __restrict__ sbox, u64* __restrict__ mask) {
#pragma clang fp contract(off)
    int w = blockIdx.x, b = blockIdx.y, tid = threadIdx.x;
    __shared__ float4 cbox[64];
    __shared__ float car[64];
    if (tid < 64) {
        int j = w * 64 + tid;
        float4 bx = make_float4(0.f, 0.f, 0.f, 0.f);
        if (j < TOPK) bx = ((const float4*)sbox)[(size_t)b * TOPK + j];
        cbox[tid] = bx;
        car[tid] = (bx.z - bx.x) * (bx.w - bx.y);
    }
    __syncthreads();
    for (int i = tid; i < TOPK; i += 256) {
        u64 m = 0;
        if (w * 64 + 63 > i) {  // word has at least one j > i
            const float4 bx = ((const float4*)sbox)[(size_t)b * TOPK + i];
            float x1i = bx.x, y1i = bx.y, x2i = bx.z, y2i = bx.w;
            float ai = (x2i - x1i) * (y2i - y1i);
            for (int j2 = 0; j2 < 64; ++j2) {
                int j = w * 64 + j2;
                float4 cb = cbox[j2];
                float xx1 = fmaxf(cb.x, x1i);
                float yy1 = fmaxf(cb.y, y1i);
                float xx2 = fminf(cb.z, x2i);
                float yy2 = fminf(cb.w, y2i);
                float iw = fmaxf(xx2 - xx1, 0.0f);
                float ih = fmaxf(yy2 - yy1, 0.0f);
                float inter = iw * ih;
                float iou = inter / ((car[j2] + ai) - inter);
                if ((iou > 0.2f) && (j > i)) m |= (1ULL << j2);
            }
        }
        mask[((size_t)b * TOPK + i) * NWORDS + w] = m;
    }
}

// ---------------- NMS phase 2: serial sweep, one wave per batch ----------------
// No cross-lane data movement in the loop: lane w owns act word w AND mask row
// word w. Decision bit lives on lane i>>6; __any() broadcasts it via SGPR.
// If kept: every lane ANDs its own word. Loads prefetched PF deep.
__global__ __launch_bounds__(64) void sweep_kernel(
    const u64* __restrict__ mask, const float* __restrict__ sscore,
    const float* __restrict__ sbox, float* __restrict__ out) {
    int b = blockIdx.x, lane = threadIdx.x;

    // build initial active mask from validity (score > 0); lanes >= NWORDS keep act=0
    u64 act = 0;
    for (int c = 0; c < NWORDS; ++c) {
        int r = c * 64 + lane;
        bool v = (r < TOPK) && (sscore[(size_t)b * TOPK + r] > 0.0f);
        u64 m = __ballot(v);
        if (lane == c) act = m;
    }

    int lw = (lane < NWORDS) ? lane : 0;   // clamp: lanes >= NWORDS read word 0 (unused)
    const u64* mrow = mask + (size_t)b * TOPK * NWORDS + lw;

    u64 buf[PF];
#pragma unroll
    for (int t = 0; t < PF; ++t) buf[t] = mrow[(size_t)t * NWORDS];

    for (int base = 0; base < TOPK; base += PF) {
#pragma unroll
        for (int t = 0; t < PF; ++t) {
            int i = base + t;
            u64 row = buf[t];
            int nxt = i + PF;
            buf[t] = (nxt < TOPK) ? mrow[(size_t)nxt * NWORDS] : 0ULL;
            // rows i >= TOPK (tail of last block): act bits are 0 -> no-op
            bool mybit = (lane == (i >> 6)) && ((act >> (i & 63)) & 1ULL);
            if (__any(mybit)) act &= ~row;
        }
    }

    // epilogue: act == keep bitmap; rank by prefix popcount, write compacted rows
    __shared__ u64 aw[NWORDS];
    __shared__ u32 pfx[NWORDS + 1];
    if (lane < NWORDS) aw[lane] = act;
    __syncthreads();
    if (lane == 0) {
        u32 acc = 0;
        for (int wd = 0; wd < NWORDS; ++wd) { pfx[wd] = acc; acc += (u32)__popcll(aw[wd]); }
        pfx[NWORDS] = acc;
    }
    __syncthreads();
    for (int r = lane; r < TOPK; r += 64) {
        int wd = r >> 6;
        u64 word = aw[wd];
        if ((word >> (r & 63)) & 1ULL) {
            u32 rank = pfx[wd] + (u32)__popcll(word & ((1ULL << (r & 63)) - 1ULL));
            float sc = sscore[(size_t)b * TOPK + r];
            float4 bx = ((const float4*)sbox)[(size_t)b * TOPK + r];
            size_t base_o = (((size_t)b * 2 + 1) * TOPK + (size_t)rank) * 5;
            out[base_o + 0] = sc;
            out[base_o + 1] = bx.x;
            out[base_o + 2] = bx.y;
            out[base_o + 3] = bx.z;
            out[base_o + 4] = bx.w;
        }
    }
}

extern "C" void kernel_launch(void* const* d_in, const int* in_sizes, int n_in,
                              void* d_out, int out_size, void* d_ws, size_t ws_size,
                              hipStream_t stream) {
    const float* loc   = (const float*)d_in[0];
    const float* conf  = (const float*)d_in[1];
    const float* prior = (const float*)d_in[2];
    float* out = (float*)d_out;
    char* ws = (char*)d_ws;

    // ws layout (bytes):
    //   mask   0        .. 9216000   (32*1500*24*8) — hist (512KB) aliases its head
    //   counts 9216000  (+128)
    //   tbin   9216128  (+128)
    //   keys   9216256  (+524288)
    //   sscore 9740544  (+192000)
    //   sbox   9932544  (+768000)  -> total 10,700,544 B
    u64* mask_buf = (u64*)(ws + 0);
    u32* hist     = (u32*)(ws + 0);            // dead after thresh_kernel
    u32* counts   = (u32*)(ws + 9216000);
    int* tbin     = (int*)(ws + 9216128);
    u64* keys     = (u64*)(ws + 9216256);
    float* sscore = (float*)(ws + 9740544);
    float* sbox   = (float*)(ws + 9932544);

    zero_kernel<<<2048, 256, 0, stream>>>(hist, NBINS * NUM_B, counts, NUM_B,
                                          (u32*)out, 480000);
    hist_kernel<<<dim3(300, 32), 256, 0, stream>>>(conf, hist);
    thresh_kernel<<<32, 256, 0, stream>>>(hist, tbin);
    compact_kernel<<<dim3(300, 32), 256, 0, stream>>>(conf, tbin, counts, keys);
    sort_decode_kernel<<<32, 256, 0, stream>>>(keys, counts, loc, prior, sscore, sbox);
    mask_kernel<<<dim3(NWORDS, 32), 256, 0, stream>>>(sbox, mask_buf);
    sweep_kernel<<<32, 64, 0, stream>>>(mask_buf, sscore, sbox, out);
}

// Round 6
// 506.213 us; speedup vs baseline: 1.8505x; 1.0515x over previous
//
#include <hip/hip_runtime.h>
#include <stdint.h>

typedef unsigned long long u64;
typedef unsigned int u32;

#define NUM_B 32
#define NUM_P 76800
#define TOPK 1500
#define NBINS 4096   // linear bins: bin = min(int(s*4096), 4095); uniform occupancy
#define CAP 2048
#define NWORDS 24    // ceil(1500/64) u64 words per mask row == number of 64-row tiles

__device__ __forceinline__ u32 fbits(float f) { return __float_as_uint(f); }
// Monotone non-decreasing in s => threshold-bin selection is order-correct.
__device__ __forceinline__ int binOf(float s) {
    int b = (int)(s * (float)NBINS);
    return (b > NBINS - 1) ? NBINS - 1 : b;
}
// wave-uniform lane read of a u64 register
__device__ __forceinline__ u64 readlane64(u64 v, int l) {
    u32 lo = (u32)__builtin_amdgcn_readlane((int)(u32)(v & 0xffffffffu), l);
    u32 hi = (u32)__builtin_amdgcn_readlane((int)(u32)(v >> 32), l);
    return ((u64)hi << 32) | lo;
}

// ---------------- zero out + scratch ----------------
__global__ void zero_kernel(u32* a, int n, u32* b, int nb, u32* c, int nc) {
    int i = blockIdx.x * blockDim.x + threadIdx.x;
    int stride = gridDim.x * blockDim.x;
    for (int t = i; t < n; t += stride) a[t] = 0;
    for (int t = i; t < nb; t += stride) b[t] = 0;
    for (int t = i; t < nc; t += stride) c[t] = 0;
}

// ---------------- linear histogram of class-1 scores ----------------
__global__ void hist_kernel(const float* __restrict__ conf, u32* __restrict__ hist) {
    int p = blockIdx.x * blockDim.x + threadIdx.x;
    int b = blockIdx.y;
    if (p >= NUM_P) return;
    float s = conf[((size_t)b * NUM_P + p) * 2 + 1];
    if (s > 0.01f) {
        atomicAdd(&hist[(size_t)b * NBINS + binOf(s)], 1u);
    }
}

// ---------------- find per-batch threshold bin: smallest bin T with suffix count >= TOPK ----
__global__ void thresh_kernel(const u32* __restrict__ hist, int* __restrict__ tbin) {
    int b = blockIdx.x;
    int tid = threadIdx.x;
    __shared__ u32 vals[256];
    __shared__ int s_min;
    u32 total = 0;
    for (int c = 0; c < NBINS / 256; ++c) {
        if (tid == 0) s_min = 256;
        int bin = NBINS - 1 - (c * 256 + tid);
        u32 v = hist[(size_t)b * NBINS + bin];
        __syncthreads();
        vals[tid] = v;
        __syncthreads();
        for (int off = 1; off < 256; off <<= 1) {
            u32 add = (tid >= off) ? vals[tid - off] : 0;
            __syncthreads();
            vals[tid] += add;
            __syncthreads();
        }
        u32 cum = total + vals[tid];
        if (cum >= TOPK) atomicMin(&s_min, tid);
        __syncthreads();
        if (s_min < 256) {
            if (tid == 0) tbin[b] = NBINS - 1 - (c * 256 + s_min);
            return;
        }
        total += vals[255];
    }
    if (tid == 0) tbin[b] = 0;
}

// ---------------- compact candidate keys (score_bits<<32 | ~index), 1 atomic/block ----------
__global__ __launch_bounds__(256) void compact_kernel(
    const float* __restrict__ conf, const int* __restrict__ tbin,
    u32* __restrict__ counts, u64* __restrict__ keys) {
    int p = blockIdx.x * blockDim.x + threadIdx.x;
    int b = blockIdx.y;
    int tid = threadIdx.x;
    int wave = tid >> 6, lane = tid & 63;

    bool v = false;
    float s = 0.f;
    if (p < NUM_P) {
        s = conf[((size_t)b * NUM_P + p) * 2 + 1];
        if (s > 0.01f) v = (binOf(s) >= tbin[b]);
    }

    u64 mask = __ballot(v);
    u32 lane_prefix = (u32)__popcll(mask & ((1ULL << lane) - 1ULL));
    u32 wave_cnt = (u32)__popcll(mask);

    __shared__ u32 wcnt[4];
    __shared__ u32 s_base;
    if (lane == 0) wcnt[wave] = wave_cnt;
    __syncthreads();
    if (tid == 0) {
        u32 tot = wcnt[0] + wcnt[1] + wcnt[2] + wcnt[3];
        s_base = (tot > 0) ? atomicAdd(&counts[b], tot) : 0u;
    }
    __syncthreads();
    if (v) {
        u32 woff = 0;
        for (int w = 0; w < wave; ++w) woff += wcnt[w];
        u32 pos = s_base + woff + lane_prefix;
        if (pos < CAP) keys[(size_t)b * CAP + pos] = ((u64)fbits(s) << 32) | (u32)(~p);
    }
}

// ---------------- bitonic sort 2048 keys desc, take top-1500, gather+decode boxes ----------
__global__ __launch_bounds__(256) void sort_decode_kernel(
    const u64* __restrict__ keys, const u32* __restrict__ counts,
    const float* __restrict__ loc, const float* __restrict__ prior,
    float* __restrict__ sscore, float* __restrict__ sbox) {
#pragma clang fp contract(off)
    int b = blockIdx.x, tid = threadIdx.x;
    __shared__ u64 k[CAP];
    int n = (int)min(counts[b], (u32)CAP);
    for (int t = tid; t < CAP; t += 256)
        k[t] = (t < n) ? keys[(size_t)b * CAP + t] : 0ULL;
    __syncthreads();
    for (int kk = 2; kk <= CAP; kk <<= 1) {
        for (int j = kk >> 1; j > 0; j >>= 1) {
            for (int t = tid; t < CAP; t += 256) {
                int l = t ^ j;
                if (l > t) {
                    u64 a = k[t], c = k[l];
                    bool desc = ((t & kk) == 0);
                    if (desc ? (a < c) : (a > c)) { k[t] = c; k[l] = a; }
                }
            }
            __syncthreads();
        }
    }
    for (int r = tid; r < TOPK; r += 256) {
        u64 key = k[r];
        float sc = 0.f, x1 = 0.f, y1 = 0.f, x2 = 0.f, y2 = 0.f;
        if (key != 0ULL) {
            u32 pidx = ~(u32)key;
            sc = __uint_as_float((u32)(key >> 32));
            const float* lp = &loc[((size_t)b * NUM_P + pidx) * 4];
            const float* pp = &prior[(size_t)pidx * 4];
            float lx = lp[0], ly = lp[1], lw = lp[2], lh = lp[3];
            float pcx = pp[0], pcy = pp[1], pw = pp[2], ph = pp[3];
            float cx = pcx + (lx * 0.1f) * pw;
            float cy = pcy + (ly * 0.1f) * ph;
            float w  = pw * expf(lw * 0.2f);
            float h  = ph * expf(lh * 0.2f);
            x1 = cx - w * 0.5f;
            y1 = cy - h * 0.5f;
            x2 = x1 + w;
            y2 = y1 + h;
        }
        sscore[(size_t)b * TOPK + r] = sc;
        float* bx = &sbox[((size_t)b * TOPK + r) * 4];
        bx[0] = x1; bx[1] = y1; bx[2] = x2; bx[3] = y2;
    }
}

// ---------------- NMS phase 1: suppression bitmask, fully parallel ----------------
__global__ __launch_bounds__(256) void mask_kernel(
    const float* __restrict__ sbox, u64* __restrict__ mask) {
#pragma clang fp contract(off)
    int w = blockIdx.x, b = blockIdx.y, tid = threadIdx.x;
    __shared__ float4 cbox[64];
    __shared__ float car[64];
    if (tid < 64) {
        int j = w * 64 + tid;
        float4 bx = make_float4(0.f, 0.f, 0.f, 0.f);
        if (j < TOPK) bx = ((const float4*)sbox)[(size_t)b * TOPK + j];
        cbox[tid] = bx;
        car[tid] = (bx.z - bx.x) * (bx.w - bx.y);
    }
    __syncthreads();
    for (int i = tid; i < TOPK; i += 256) {
        u64 m = 0;
        if (w * 64 + 63 > i) {  // word has at least one j > i
            const float4 bx = ((const float4*)sbox)[(size_t)b * TOPK + i];
            float x1i = bx.x, y1i = bx.y, x2i = bx.z, y2i = bx.w;
            float ai = (x2i - x1i) * (y2i - y1i);
            for (int j2 = 0; j2 < 64; ++j2) {
                int j = w * 64 + j2;
                float4 cb = cbox[j2];
                float xx1 = fmaxf(cb.x, x1i);
                float yy1 = fmaxf(cb.y, y1i);
                float xx2 = fminf(cb.z, x2i);
                float yy2 = fminf(cb.w, y2i);
                float iw = fmaxf(xx2 - xx1, 0.0f);
                float ih = fmaxf(yy2 - yy1, 0.0f);
                float inter = iw * ih;
                float iou = inter / ((car[j2] + ai) - inter);
                if ((iou > 0.2f) && (j > i)) m |= (1ULL << j2);
            }
        }
        mask[((size_t)b * TOPK + i) * NWORDS + w] = m;
    }
}

// ---------------- NMS phase 2: tiled serial sweep, one wave per batch ----------------
// Serial work ~ #kept rows, not #rows. Per 64-row tile:
//  - diag word (tile's own 64x64 block) preloaded per lane, one tile ahead;
//  - intra-tile greedy on wave-uniform scalars (ffs + v_readlane, no memory);
//  - kept rows' full mask rows applied to act in groups of 8 independent loads.
__global__ __launch_bounds__(64) void sweep_kernel(
    const u64* __restrict__ mask, const float* __restrict__ sscore,
    const float* __restrict__ sbox, float* __restrict__ out) {
    int b = blockIdx.x, lane = threadIdx.x;

    // initial active bitmap from validity (score > 0); lane w owns act word w
    u64 act = 0;
    for (int c = 0; c < NWORDS; ++c) {
        int r = c * 64 + lane;
        bool v = (r < TOPK) && (sscore[(size_t)b * TOPK + r] > 0.0f);
        u64 m = __ballot(v);
        if (lane == c) act = m;
    }

    int lw = (lane < NWORDS) ? lane : 0;   // lanes >= NWORDS shadow word 0 (their act==0)
    const u64* mbase = mask + (size_t)b * TOPK * NWORDS;

    // diag word for tile 0
    int r0 = lane;
    u64 diag = (r0 < TOPK) ? mbase[(size_t)r0 * NWORDS + 0] : 0ULL;

    for (int T = 0; T < NWORDS; ++T) {
        // prefetch next tile's diag (independent of this tile's work)
        u64 diag_next = 0ULL;
        if (T + 1 < NWORDS) {
            int rn = (T + 1) * 64 + lane;
            diag_next = (rn < TOPK) ? mbase[(size_t)rn * NWORDS + (T + 1)] : 0ULL;
        }

        // wave-uniform copy of act word T
        u64 actw = readlane64(act, T);

        // intra-tile greedy: iterations == #kept in tile
        u64 kept = 0;
        u64 rem = actw;
        while (rem) {
            int i = __ffsll(rem) - 1;
            kept |= (1ULL << i);
            rem &= rem - 1;                 // pop row i
            u64 di = readlane64(diag, i);   // row i's diagonal suppression word
            rem &= ~di;                     // bulk-remove suppressed rows
        }
        if (lane == T) act = kept;

        // apply kept rows' full masks to all act words, 8 independent loads per group
        u64 kb = kept;
        while (kb) {
            int idx[8];
            int cnt = 0;
            while (kb && cnt < 8) { idx[cnt++] = __ffsll(kb) - 1; kb &= kb - 1; }
            u64 g[8];
#pragma unroll
            for (int t = 0; t < 8; ++t)
                g[t] = (t < cnt) ? mbase[(size_t)(T * 64 + idx[t]) * NWORDS + lw] : 0ULL;
#pragma unroll
            for (int t = 0; t < 8; ++t) act &= ~g[t];
        }

        diag = diag_next;
    }

    // epilogue: act == keep bitmap; rank by prefix popcount, write compacted rows
    __shared__ u64 aw[NWORDS];
    __shared__ u32 pfx[NWORDS + 1];
    if (lane < NWORDS) aw[lane] = act;
    __syncthreads();
    if (lane == 0) {
        u32 acc = 0;
        for (int wd = 0; wd < NWORDS; ++wd) { pfx[wd] = acc; acc += (u32)__popcll(aw[wd]); }
        pfx[NWORDS] = acc;
    }
    __syncthreads();
    for (int r = lane; r < TOPK; r += 64) {
        int wd = r >> 6;
        u64 word = aw[wd];
        if ((word >> (r & 63)) & 1ULL) {
            u32 rank = pfx[wd] + (u32)__popcll(word & ((1ULL << (r & 63)) - 1ULL));
            float sc = sscore[(size_t)b * TOPK + r];
            float4 bx = ((const float4*)sbox)[(size_t)b * TOPK + r];
            size_t base_o = (((size_t)b * 2 + 1) * TOPK + (size_t)rank) * 5;
            out[base_o + 0] = sc;
            out[base_o + 1] = bx.x;
            out[base_o + 2] = bx.y;
            out[base_o + 3] = bx.z;
            out[base_o + 4] = bx.w;
        }
    }
}

extern "C" void kernel_launch(void* const* d_in, const int* in_sizes, int n_in,
                              void* d_out, int out_size, void* d_ws, size_t ws_size,
                              hipStream_t stream) {
    const float* loc   = (const float*)d_in[0];
    const float* conf  = (const float*)d_in[1];
    const float* prior = (const float*)d_in[2];
    float* out = (float*)d_out;
    char* ws = (char*)d_ws;

    // ws layout (bytes):
    //   mask   0        .. 9216000   (32*1500*24*8) — hist (512KB) aliases its head
    //   counts 9216000  (+128)
    //   tbin   9216128  (+128)
    //   keys   9216256  (+524288)
    //   sscore 9740544  (+192000)
    //   sbox   9932544  (+768000)  -> total 10,700,544 B
    u64* mask_buf = (u64*)(ws + 0);
    u32* hist     = (u32*)(ws + 0);            // dead after thresh_kernel
    u32* counts   = (u32*)(ws + 9216000);
    int* tbin     = (int*)(ws + 9216128);
    u64* keys     = (u64*)(ws + 9216256);
    float* sscore = (float*)(ws + 9740544);
    float* sbox   = (float*)(ws + 9932544);

    zero_kernel<<<2048, 256, 0, stream>>>(hist, NBINS * NUM_B, counts, NUM_B,
                                          (u32*)out, 480000);
    hist_kernel<<<dim3(300, 32), 256, 0, stream>>>(conf, hist);
    thresh_kernel<<<32, 256, 0, stream>>>(hist, tbin);
    compact_kernel<<<dim3(300, 32), 256, 0, stream>>>(conf, tbin, counts, keys);
    sort_decode_kernel<<<32, 256, 0, stream>>>(keys, counts, loc, prior, sscore, sbox);
    mask_kernel<<<dim3(NWORDS, 32), 256, 0, stream>>>(sbox, mask_buf);
    sweep_kernel<<<32, 64, 0, stream>>>(mask_buf, sscore, sbox, out);
}

// Round 7
// 328.877 us; speedup vs baseline: 2.8483x; 1.5392x over previous
//
#include <hip/hip_runtime.h>
#include <stdint.h>

typedef unsigned long long u64;
typedef unsigned int u32;

#define NUM_B 32
#define NUM_P 76800
#define TOPK 1500
#define NBINS 4096   // linear bins: bin = min(int(s*4096), 4095)
#define CAP 2048
#define NWORDS 24    // ceil(1500/64) u64 words per mask row == number of 64-row tiles
#define CPAD 32      // counts padded to 128 B to kill same-line atomic serialization
#define HSLICES 8    // private histogram slices per batch (no global atomics)
#define HCHUNK (NUM_P / HSLICES)   // 9600 priors per slice

__device__ __forceinline__ u32 fbits(float f) { return __float_as_uint(f); }
// Monotone non-decreasing in s => threshold-bin selection is order-correct.
__device__ __forceinline__ int binOf(float s) {
    int b = (int)(s * (float)NBINS);
    return (b > NBINS - 1) ? NBINS - 1 : b;
}
// wave-uniform lane read of a u64 register
__device__ __forceinline__ u64 readlane64(u64 v, int l) {
    u32 lo = (u32)__builtin_amdgcn_readlane((int)(u32)(v & 0xffffffffu), l);
    u32 hi = (u32)__builtin_amdgcn_readlane((int)(u32)(v >> 32), l);
    return ((u64)hi << 32) | lo;
}

// ---------------- zero counts + output ----------------
__global__ void zero_kernel(u32* a, int n, u32* c, int nc) {
    int i = blockIdx.x * blockDim.x + threadIdx.x;
    int stride = gridDim.x * blockDim.x;
    for (int t = i; t < n; t += stride) a[t] = 0;
    for (int t = i; t < nc; t += stride) c[t] = 0;
}

// ---------------- histogram: LDS-private per (batch, slice), full overwrite ----------------
__global__ __launch_bounds__(256) void hist_kernel(const float4* __restrict__ conf4,
                                                   u32* __restrict__ hist) {
    int c = blockIdx.x, b = blockIdx.y, tid = threadIdx.x;
    __shared__ u32 h[NBINS];
    for (int i = tid; i < NBINS; i += 256) h[i] = 0;
    __syncthreads();
    const float4* base = conf4 + (size_t)b * (NUM_P / 2) + (size_t)c * (HCHUNK / 2);
    for (int i = tid; i < HCHUNK / 2; i += 256) {
        float4 v = base[i];           // 2 priors: (c0,c1,c0,c1); class-1 = .y/.w
        if (v.y > 0.01f) atomicAdd(&h[binOf(v.y)], 1u);
        if (v.w > 0.01f) atomicAdd(&h[binOf(v.w)], 1u);
    }
    __syncthreads();
    u32* outp = hist + ((size_t)b * HSLICES + c) * NBINS;
    for (int i = tid; i < NBINS; i += 256) outp[i] = h[i];
}

// ---------------- find per-batch threshold bin: smallest bin T with suffix count >= TOPK ----
__global__ void thresh_kernel(const u32* __restrict__ hist, int* __restrict__ tbin) {
    int b = blockIdx.x;
    int tid = threadIdx.x;
    const u32* hb = hist + (size_t)b * HSLICES * NBINS;
    __shared__ u32 vals[256];
    __shared__ int s_min;
    u32 total = 0;
    for (int c = 0; c < NBINS / 256; ++c) {
        if (tid == 0) s_min = 256;
        int bin = NBINS - 1 - (c * 256 + tid);
        u32 v = 0;
#pragma unroll
        for (int s = 0; s < HSLICES; ++s) v += hb[(size_t)s * NBINS + bin];
        __syncthreads();
        vals[tid] = v;
        __syncthreads();
        for (int off = 1; off < 256; off <<= 1) {
            u32 add = (tid >= off) ? vals[tid - off] : 0;
            __syncthreads();
            vals[tid] += add;
            __syncthreads();
        }
        u32 cum = total + vals[tid];
        if (cum >= TOPK) atomicMin(&s_min, tid);
        __syncthreads();
        if (s_min < 256) {
            if (tid == 0) tbin[b] = NBINS - 1 - (c * 256 + s_min);
            return;
        }
        total += vals[255];
    }
    if (tid == 0) tbin[b] = 0;
}

// ---------------- compact candidate keys: float4 loads, padded counters ----------------
// keys are fully sorted later, so intra-batch order is irrelevant — only uniqueness.
__global__ __launch_bounds__(256) void compact_kernel(
    const float4* __restrict__ conf4, const int* __restrict__ tbin,
    u32* __restrict__ counts, u64* __restrict__ keys) {
    int b = blockIdx.y;
    int tid = threadIdx.x;
    int lane = tid & 63, wave = tid >> 6;
    int f4 = blockIdx.x * 256 + tid;            // float4 index within batch (2 priors)
    float4 c = conf4[(size_t)b * (NUM_P / 2) + f4];
    int tb = tbin[b];
    int p0 = f4 * 2, p1 = p0 + 1;
    bool v0 = (c.y > 0.01f) && (binOf(c.y) >= tb);
    bool v1 = (c.w > 0.01f) && (binOf(c.w) >= tb);

    u64 m0 = __ballot(v0), m1 = __ballot(v1);
    u32 c0 = (u32)__popcll(m0);
    u64 below = (1ULL << lane) - 1ULL;
    u32 off0 = (u32)__popcll(m0 & below);
    u32 off1 = c0 + (u32)__popcll(m1 & below);
    u32 wtot = c0 + (u32)__popcll(m1);

    __shared__ u32 wcnt[4];
    __shared__ u32 s_base;
    if (lane == 0) wcnt[wave] = wtot;
    __syncthreads();
    if (tid == 0) {
        u32 tot = wcnt[0] + wcnt[1] + wcnt[2] + wcnt[3];
        s_base = (tot > 0) ? atomicAdd(&counts[(size_t)b * CPAD], tot) : 0u;
    }
    __syncthreads();
    u32 woff = 0;
    for (int w = 0; w < wave; ++w) woff += wcnt[w];
    if (v0) {
        u32 pos = s_base + woff + off0;
        if (pos < CAP) keys[(size_t)b * CAP + pos] = ((u64)fbits(c.y) << 32) | (u32)(~p0);
    }
    if (v1) {
        u32 pos = s_base + woff + off1;
        if (pos < CAP) keys[(size_t)b * CAP + pos] = ((u64)fbits(c.w) << 32) | (u32)(~p1);
    }
}

// ---------------- bitonic sort 2048 keys desc, take top-1500, gather+decode boxes ----------
__global__ __launch_bounds__(256) void sort_decode_kernel(
    const u64* __restrict__ keys, const u32* __restrict__ counts,
    const float* __restrict__ loc, const float* __restrict__ prior,
    float* __restrict__ sscore, float* __restrict__ sbox) {
#pragma clang fp contract(off)
    int b = blockIdx.x, tid = threadIdx.x;
    __shared__ u64 k[CAP];
    int n = (int)min(counts[(size_t)b * CPAD], (u32)CAP);
    for (int t = tid; t < CAP; t += 256)
        k[t] = (t < n) ? keys[(size_t)b * CAP + t] : 0ULL;
    __syncthreads();
    for (int kk = 2; kk <= CAP; kk <<= 1) {
        for (int j = kk >> 1; j > 0; j >>= 1) {
            for (int t = tid; t < CAP; t += 256) {
                int l = t ^ j;
                if (l > t) {
                    u64 a = k[t], c = k[l];
                    bool desc = ((t & kk) == 0);
                    if (desc ? (a < c) : (a > c)) { k[t] = c; k[l] = a; }
                }
            }
            __syncthreads();
        }
    }
    for (int r = tid; r < TOPK; r += 256) {
        u64 key = k[r];
        float sc = 0.f, x1 = 0.f, y1 = 0.f, x2 = 0.f, y2 = 0.f;
        if (key != 0ULL) {
            u32 pidx = ~(u32)key;
            sc = __uint_as_float((u32)(key >> 32));
            const float* lp = &loc[((size_t)b * NUM_P + pidx) * 4];
            const float* pp = &prior[(size_t)pidx * 4];
            float lx = lp[0], ly = lp[1], lw = lp[2], lh = lp[3];
            float pcx = pp[0], pcy = pp[1], pw = pp[2], ph = pp[3];
            float cx = pcx + (lx * 0.1f) * pw;
            float cy = pcy + (ly * 0.1f) * ph;
            float w  = pw * expf(lw * 0.2f);
            float h  = ph * expf(lh * 0.2f);
            x1 = cx - w * 0.5f;
            y1 = cy - h * 0.5f;
            x2 = x1 + w;
            y2 = y1 + h;
        }
        sscore[(size_t)b * TOPK + r] = sc;
        float* bx = &sbox[((size_t)b * TOPK + r) * 4];
        bx[0] = x1; bx[1] = y1; bx[2] = x2; bx[3] = y2;
    }
}

// ---------------- NMS phase 1: suppression bitmask, fully parallel ----------------
__global__ __launch_bounds__(256) void mask_kernel(
    const float* __restrict__ sbox, u64* __restrict__ mask) {
#pragma clang fp contract(off)
    int w = blockIdx.x, b = blockIdx.y, tid = threadIdx.x;
    __shared__ float4 cbox[64];
    __shared__ float car[64];
    if (tid < 64) {
        int j = w * 64 + tid;
        float4 bx = make_float4(0.f, 0.f, 0.f, 0.f);
        if (j < TOPK) bx = ((const float4*)sbox)[(size_t)b * TOPK + j];
        cbox[tid] = bx;
        car[tid] = (bx.z - bx.x) * (bx.w - bx.y);
    }
    __syncthreads();
    for (int i = tid; i < TOPK; i += 256) {
        u64 m = 0;
        if (w * 64 + 63 > i) {  // word has at least one j > i
            const float4 bx = ((const float4*)sbox)[(size_t)b * TOPK + i];
            float x1i = bx.x, y1i = bx.y, x2i = bx.z, y2i = bx.w;
            float ai = (x2i - x1i) * (y2i - y1i);
            for (int j2 = 0; j2 < 64; ++j2) {
                int j = w * 64 + j2;
                float4 cb = cbox[j2];
                float xx1 = fmaxf(cb.x, x1i);
                float yy1 = fmaxf(cb.y, y1i);
                float xx2 = fminf(cb.z, x2i);
                float yy2 = fminf(cb.w, y2i);
                float iw = fmaxf(xx2 - xx1, 0.0f);
                float ih = fmaxf(yy2 - yy1, 0.0f);
                float inter = iw * ih;
                float iou = inter / ((car[j2] + ai) - inter);
                if ((iou > 0.2f) && (j > i)) m |= (1ULL << j2);
            }
        }
        mask[((size_t)b * TOPK + i) * NWORDS + w] = m;
    }
}

// ---------------- NMS phase 2: tiled serial sweep, one wave per batch ----------------
__global__ __launch_bounds__(64) void sweep_kernel(
    const u64* __restrict__ mask, const float* __restrict__ sscore,
    const float* __restrict__ sbox, float* __restrict__ out) {
    int b = blockIdx.x, lane = threadIdx.x;

    u64 act = 0;
    for (int c = 0; c < NWORDS; ++c) {
        int r = c * 64 + lane;
        bool v = (r < TOPK) && (sscore[(size_t)b * TOPK + r] > 0.0f);
        u64 m = __ballot(v);
        if (lane == c) act = m;
    }

    int lw = (lane < NWORDS) ? lane : 0;
    const u64* mbase = mask + (size_t)b * TOPK * NWORDS;

    int r0 = lane;
    u64 diag = (r0 < TOPK) ? mbase[(size_t)r0 * NWORDS + 0] : 0ULL;

    for (int T = 0; T < NWORDS; ++T) {
        u64 diag_next = 0ULL;
        if (T + 1 < NWORDS) {
            int rn = (T + 1) * 64 + lane;
            diag_next = (rn < TOPK) ? mbase[(size_t)rn * NWORDS + (T + 1)] : 0ULL;
        }

        u64 actw = readlane64(act, T);

        u64 kept = 0;
        u64 rem = actw;
        while (rem) {
            int i = __ffsll(rem) - 1;
            kept |= (1ULL << i);
            rem &= rem - 1;
            u64 di = readlane64(diag, i);
            rem &= ~di;
        }
        if (lane == T) act = kept;

        u64 kb = kept;
        while (kb) {
            int idx[8];
            int cnt = 0;
            while (kb && cnt < 8) { idx[cnt++] = __ffsll(kb) - 1; kb &= kb - 1; }
            u64 g[8];
#pragma unroll
            for (int t = 0; t < 8; ++t)
                g[t] = (t < cnt) ? mbase[(size_t)(T * 64 + idx[t]) * NWORDS + lw] : 0ULL;
#pragma unroll
            for (int t = 0; t < 8; ++t) act &= ~g[t];
        }

        diag = diag_next;
    }

    __shared__ u64 aw[NWORDS];
    __shared__ u32 pfx[NWORDS + 1];
    if (lane < NWORDS) aw[lane] = act;
    __syncthreads();
    if (lane == 0) {
        u32 acc = 0;
        for (int wd = 0; wd < NWORDS; ++wd) { pfx[wd] = acc; acc += (u32)__popcll(aw[wd]); }
        pfx[NWORDS] = acc;
    }
    __syncthreads();
    for (int r = lane; r < TOPK; r += 64) {
        int wd = r >> 6;
        u64 word = aw[wd];
        if ((word >> (r & 63)) & 1ULL) {
            u32 rank = pfx[wd] + (u32)__popcll(word & ((1ULL << (r & 63)) - 1ULL));
            float sc = sscore[(size_t)b * TOPK + r];
            float4 bx = ((const float4*)sbox)[(size_t)b * TOPK + r];
            size_t base_o = (((size_t)b * 2 + 1) * TOPK + (size_t)rank) * 5;
            out[base_o + 0] = sc;
            out[base_o + 1] = bx.x;
            out[base_o + 2] = bx.y;
            out[base_o + 3] = bx.z;
            out[base_o + 4] = bx.w;
        }
    }
}

extern "C" void kernel_launch(void* const* d_in, const int* in_sizes, int n_in,
                              void* d_out, int out_size, void* d_ws, size_t ws_size,
                              hipStream_t stream) {
    const float* loc   = (const float*)d_in[0];
    const float* conf  = (const float*)d_in[1];
    const float* prior = (const float*)d_in[2];
    float* out = (float*)d_out;
    char* ws = (char*)d_ws;

    // ws layout (bytes) with lifetime-based aliasing into the mask region:
    //   mask   [0, 9216000)           written by mask_kernel, read by sweep
    //   hist   [0, 4194304)           32*8*4096 u32 — dead after thresh (full overwrite, no zeroing)
    //   keys   [4194304, 4718592)     dead after sort_decode
    //   counts [4718592, 4722688)     32*CPAD u32 — dead after sort_decode
    //   tbin   [4722688, 4722816)     dead after compact
    //   sscore [9216000, 9408000)
    //   sbox   [9408000, 10176000)    total 10,176,000 B
    u64* mask_buf = (u64*)(ws + 0);
    u32* hist     = (u32*)(ws + 0);
    u64* keys     = (u64*)(ws + 4194304);
    u32* counts   = (u32*)(ws + 4718592);
    int* tbin     = (int*)(ws + 4722688);
    float* sscore = (float*)(ws + 9216000);
    float* sbox   = (float*)(ws + 9408000);

    zero_kernel<<<512, 256, 0, stream>>>(counts, NUM_B * CPAD, (u32*)out, 480000);
    hist_kernel<<<dim3(HSLICES, 32), 256, 0, stream>>>((const float4*)conf, hist);
    thresh_kernel<<<32, 256, 0, stream>>>(hist, tbin);
    compact_kernel<<<dim3(150, 32), 256, 0, stream>>>((const float4*)conf, tbin, counts, keys);
    sort_decode_kernel<<<32, 256, 0, stream>>>(keys, counts, loc, prior, sscore, sbox);
    mask_kernel<<<dim3(NWORDS, 32), 256, 0, stream>>>(sbox, mask_buf);
    sweep_kernel<<<32, 64, 0, stream>>>(mask_buf, sscore, sbox, out);
}

// Round 8
// 277.880 us; speedup vs baseline: 3.3710x; 1.1835x over previous
//
#include <hip/hip_runtime.h>
#include <stdint.h>

typedef unsigned long long u64;
typedef unsigned int u32;

#define NUM_B 32
#define NUM_P 76800
#define TOPK 1500
#define NBINS 4096   // linear bins: bin = min(int(s*4096), 4095)
#define CAP 2048
#define NWORDS 24    // ceil(1500/64) u64 words per mask row == number of 64-row tiles
#define CPAD 32      // counts padded to 128 B to kill same-line atomic serialization
#define HSLICES 8    // private histogram slices per batch (no global atomics)
#define HCHUNK (NUM_P / HSLICES)   // 9600 priors per slice

__device__ __forceinline__ u32 fbits(float f) { return __float_as_uint(f); }
// Monotone non-decreasing in s => threshold-bin selection is order-correct.
__device__ __forceinline__ int binOf(float s) {
    int b = (int)(s * (float)NBINS);
    return (b > NBINS - 1) ? NBINS - 1 : b;
}
// wave-uniform lane read of a u64 register
__device__ __forceinline__ u64 readlane64(u64 v, int l) {
    u32 lo = (u32)__builtin_amdgcn_readlane((int)(u32)(v & 0xffffffffu), l);
    u32 hi = (u32)__builtin_amdgcn_readlane((int)(u32)(v >> 32), l);
    return ((u64)hi << 32) | lo;
}

// ---------------- zero counts + output + sscore/sbox ----------------
__global__ void zero_kernel(u32* a, int n, u32* c, int nc, u32* d, int nd) {
    int i = blockIdx.x * blockDim.x + threadIdx.x;
    int stride = gridDim.x * blockDim.x;
    for (int t = i; t < n; t += stride) a[t] = 0;
    for (int t = i; t < nc; t += stride) c[t] = 0;
    for (int t = i; t < nd; t += stride) d[t] = 0;
}

// ---------------- histogram: LDS-private per (batch, slice), full overwrite ----------------
__global__ __launch_bounds__(256) void hist_kernel(const float4* __restrict__ conf4,
                                                   u32* __restrict__ hist) {
    int c = blockIdx.x, b = blockIdx.y, tid = threadIdx.x;
    __shared__ u32 h[NBINS];
    for (int i = tid; i < NBINS; i += 256) h[i] = 0;
    __syncthreads();
    const float4* base = conf4 + (size_t)b * (NUM_P / 2) + (size_t)c * (HCHUNK / 2);
    for (int i = tid; i < HCHUNK / 2; i += 256) {
        float4 v = base[i];           // 2 priors: (c0,c1,c0,c1); class-1 = .y/.w
        if (v.y > 0.01f) atomicAdd(&h[binOf(v.y)], 1u);
        if (v.w > 0.01f) atomicAdd(&h[binOf(v.w)], 1u);
    }
    __syncthreads();
    u32* outp = hist + ((size_t)b * HSLICES + c) * NBINS;
    for (int i = tid; i < NBINS; i += 256) outp[i] = h[i];
}

// ---------------- find per-batch threshold bin: smallest bin T with suffix count >= TOPK ----
__global__ void thresh_kernel(const u32* __restrict__ hist, int* __restrict__ tbin) {
    int b = blockIdx.x;
    int tid = threadIdx.x;
    const u32* hb = hist + (size_t)b * HSLICES * NBINS;
    __shared__ u32 vals[256];
    __shared__ int s_min;
    u32 total = 0;
    for (int c = 0; c < NBINS / 256; ++c) {
        if (tid == 0) s_min = 256;
        int bin = NBINS - 1 - (c * 256 + tid);
        u32 v = 0;
#pragma unroll
        for (int s = 0; s < HSLICES; ++s) v += hb[(size_t)s * NBINS + bin];
        __syncthreads();
        vals[tid] = v;
        __syncthreads();
        for (int off = 1; off < 256; off <<= 1) {
            u32 add = (tid >= off) ? vals[tid - off] : 0;
            __syncthreads();
            vals[tid] += add;
            __syncthreads();
        }
        u32 cum = total + vals[tid];
        if (cum >= TOPK) atomicMin(&s_min, tid);
        __syncthreads();
        if (s_min < 256) {
            if (tid == 0) tbin[b] = NBINS - 1 - (c * 256 + s_min);
            return;
        }
        total += vals[255];
    }
    if (tid == 0) tbin[b] = 0;
}

// ---------------- compact candidate keys: float4 loads, padded counters ----------------
__global__ __launch_bounds__(256) void compact_kernel(
    const float4* __restrict__ conf4, const int* __restrict__ tbin,
    u32* __restrict__ counts, u64* __restrict__ keys) {
    int b = blockIdx.y;
    int tid = threadIdx.x;
    int lane = tid & 63, wave = tid >> 6;
    int f4 = blockIdx.x * 256 + tid;            // float4 index within batch (2 priors)
    float4 c = conf4[(size_t)b * (NUM_P / 2) + f4];
    int tb = tbin[b];
    int p0 = f4 * 2, p1 = p0 + 1;
    bool v0 = (c.y > 0.01f) && (binOf(c.y) >= tb);
    bool v1 = (c.w > 0.01f) && (binOf(c.w) >= tb);

    u64 m0 = __ballot(v0), m1 = __ballot(v1);
    u32 c0 = (u32)__popcll(m0);
    u64 below = (1ULL << lane) - 1ULL;
    u32 off0 = (u32)__popcll(m0 & below);
    u32 off1 = c0 + (u32)__popcll(m1 & below);
    u32 wtot = c0 + (u32)__popcll(m1);

    __shared__ u32 wcnt[4];
    __shared__ u32 s_base;
    if (lane == 0) wcnt[wave] = wtot;
    __syncthreads();
    if (tid == 0) {
        u32 tot = wcnt[0] + wcnt[1] + wcnt[2] + wcnt[3];
        s_base = (tot > 0) ? atomicAdd(&counts[(size_t)b * CPAD], tot) : 0u;
    }
    __syncthreads();
    u32 woff = 0;
    for (int w = 0; w < wave; ++w) woff += wcnt[w];
    if (v0) {
        u32 pos = s_base + woff + off0;
        if (pos < CAP) keys[(size_t)b * CAP + pos] = ((u64)fbits(c.y) << 32) | (u32)(~p0);
    }
    if (v1) {
        u32 pos = s_base + woff + off1;
        if (pos < CAP) keys[(size_t)b * CAP + pos] = ((u64)fbits(c.w) << 32) | (u32)(~p1);
    }
}

// ---------------- rank-by-count (replaces bitonic sort) + gather+decode boxes ----------
// Unique keys => rank = #{j: key_j > key_i} is the exact descending-sort position.
// Barrier-free after staging; 8 blocks/batch -> full-chip parallel.
__global__ __launch_bounds__(256) void rank_decode_kernel(
    const u64* __restrict__ keys, const u32* __restrict__ counts,
    const float* __restrict__ loc, const float* __restrict__ prior,
    float* __restrict__ sscore, float* __restrict__ sbox) {
#pragma clang fp contract(off)
    int blk = blockIdx.x, b = blockIdx.y, tid = threadIdx.x;
    __shared__ u64 k[CAP];
    int n = (int)min(counts[(size_t)b * CPAD], (u32)CAP);
    for (int t = tid; t < CAP; t += 256) {
        int idx = blk * 256 + tid - tid + t;   // == t; keep simple
        k[t] = (t < n) ? keys[(size_t)b * CAP + t] : 0ULL;
    }
    __syncthreads();

    int t = blk * 256 + tid;
    u64 mykey = k[t];
    if (mykey == 0ULL) return;   // empty slot (valid keys have score bits != 0)

    u32 rank = 0;
#pragma unroll 8
    for (int j = 0; j < CAP; ++j) rank += (k[j] > mykey) ? 1u : 0u;

    if (rank < TOPK) {
        u32 pidx = ~(u32)mykey;
        float sc = __uint_as_float((u32)(mykey >> 32));
        const float* lp = &loc[((size_t)b * NUM_P + pidx) * 4];
        const float* pp = &prior[(size_t)pidx * 4];
        float lx = lp[0], ly = lp[1], lw = lp[2], lh = lp[3];
        float pcx = pp[0], pcy = pp[1], pw = pp[2], ph = pp[3];
        float cx = pcx + (lx * 0.1f) * pw;
        float cy = pcy + (ly * 0.1f) * ph;
        float w  = pw * expf(lw * 0.2f);
        float h  = ph * expf(lh * 0.2f);
        float x1 = cx - w * 0.5f;
        float y1 = cy - h * 0.5f;
        float x2 = x1 + w;
        float y2 = y1 + h;
        sscore[(size_t)b * TOPK + rank] = sc;
        float* bx = &sbox[((size_t)b * TOPK + rank) * 4];
        bx[0] = x1; bx[1] = y1; bx[2] = x2; bx[3] = y2;
    }
}

// ---------------- NMS phase 1: suppression bitmask, fully parallel ----------------
__global__ __launch_bounds__(256) void mask_kernel(
    const float* __restrict__ sbox, u64* __restrict__ mask) {
#pragma clang fp contract(off)
    int w = blockIdx.x, b = blockIdx.y, tid = threadIdx.x;
    __shared__ float4 cbox[64];
    __shared__ float car[64];
    if (tid < 64) {
        int j = w * 64 + tid;
        float4 bx = make_float4(0.f, 0.f, 0.f, 0.f);
        if (j < TOPK) bx = ((const float4*)sbox)[(size_t)b * TOPK + j];
        cbox[tid] = bx;
        car[tid] = (bx.z - bx.x) * (bx.w - bx.y);
    }
    __syncthreads();
    for (int i = tid; i < TOPK; i += 256) {
        u64 m = 0;
        if (w * 64 + 63 > i) {  // word has at least one j > i
            const float4 bx = ((const float4*)sbox)[(size_t)b * TOPK + i];
            float x1i = bx.x, y1i = bx.y, x2i = bx.z, y2i = bx.w;
            float ai = (x2i - x1i) * (y2i - y1i);
            for (int j2 = 0; j2 < 64; ++j2) {
                int j = w * 64 + j2;
                float4 cb = cbox[j2];
                float xx1 = fmaxf(cb.x, x1i);
                float yy1 = fmaxf(cb.y, y1i);
                float xx2 = fminf(cb.z, x2i);
                float yy2 = fminf(cb.w, y2i);
                float iw = fmaxf(xx2 - xx1, 0.0f);
                float ih = fmaxf(yy2 - yy1, 0.0f);
                float inter = iw * ih;
                float iou = inter / ((car[j2] + ai) - inter);
                if ((iou > 0.2f) && (j > i)) m |= (1ULL << j2);
            }
        }
        mask[((size_t)b * TOPK + i) * NWORDS + w] = m;
    }
}

// ---------------- NMS phase 2: tiled serial sweep, one wave per batch ----------------
__global__ __launch_bounds__(64) void sweep_kernel(
    const u64* __restrict__ mask, const float* __restrict__ sscore,
    const float* __restrict__ sbox, float* __restrict__ out) {
    int b = blockIdx.x, lane = threadIdx.x;

    u64 act = 0;
    for (int c = 0; c < NWORDS; ++c) {
        int r = c * 64 + lane;
        bool v = (r < TOPK) && (sscore[(size_t)b * TOPK + r] > 0.0f);
        u64 m = __ballot(v);
        if (lane == c) act = m;
    }

    int lw = (lane < NWORDS) ? lane : 0;
    const u64* mbase = mask + (size_t)b * TOPK * NWORDS;

    int r0 = lane;
    u64 diag = (r0 < TOPK) ? mbase[(size_t)r0 * NWORDS + 0] : 0ULL;

    for (int T = 0; T < NWORDS; ++T) {
        u64 diag_next = 0ULL;
        if (T + 1 < NWORDS) {
            int rn = (T + 1) * 64 + lane;
            diag_next = (rn < TOPK) ? mbase[(size_t)rn * NWORDS + (T + 1)] : 0ULL;
        }

        u64 actw = readlane64(act, T);

        u64 kept = 0;
        u64 rem = actw;
        while (rem) {
            int i = __ffsll(rem) - 1;
            kept |= (1ULL << i);
            rem &= rem - 1;
            u64 di = readlane64(diag, i);
            rem &= ~di;
        }
        if (lane == T) act = kept;

        u64 kb = kept;
        while (kb) {
            int idx[8];
            int cnt = 0;
            while (kb && cnt < 8) { idx[cnt++] = __ffsll(kb) - 1; kb &= kb - 1; }
            u64 g[8];
#pragma unroll
            for (int t = 0; t < 8; ++t)
                g[t] = (t < cnt) ? mbase[(size_t)(T * 64 + idx[t]) * NWORDS + lw] : 0ULL;
#pragma unroll
            for (int t = 0; t < 8; ++t) act &= ~g[t];
        }

        diag = diag_next;
    }

    __shared__ u64 aw[NWORDS];
    __shared__ u32 pfx[NWORDS + 1];
    if (lane < NWORDS) aw[lane] = act;
    __syncthreads();
    if (lane == 0) {
        u32 acc = 0;
        for (int wd = 0; wd < NWORDS; ++wd) { pfx[wd] = acc; acc += (u32)__popcll(aw[wd]); }
        pfx[NWORDS] = acc;
    }
    __syncthreads();
    for (int r = lane; r < TOPK; r += 64) {
        int wd = r >> 6;
        u64 word = aw[wd];
        if ((word >> (r & 63)) & 1ULL) {
            u32 rank = pfx[wd] + (u32)__popcll(word & ((1ULL << (r & 63)) - 1ULL));
            float sc = sscore[(size_t)b * TOPK + r];
            float4 bx = ((const float4*)sbox)[(size_t)b * TOPK + r];
            size_t base_o = (((size_t)b * 2 + 1) * TOPK + (size_t)rank) * 5;
            out[base_o + 0] = sc;
            out[base_o + 1] = bx.x;
            out[base_o + 2] = bx.y;
            out[base_o + 3] = bx.z;
            out[base_o + 4] = bx.w;
        }
    }
}

extern "C" void kernel_launch(void* const* d_in, const int* in_sizes, int n_in,
                              void* d_out, int out_size, void* d_ws, size_t ws_size,
                              hipStream_t stream) {
    const float* loc   = (const float*)d_in[0];
    const float* conf  = (const float*)d_in[1];
    const float* prior = (const float*)d_in[2];
    float* out = (float*)d_out;
    char* ws = (char*)d_ws;

    // ws layout (bytes) with lifetime-based aliasing into the mask region:
    //   mask   [0, 9216000)           written by mask_kernel, read by sweep
    //   hist   [0, 4194304)           32*8*4096 u32 — dead after thresh (full overwrite)
    //   keys   [4194304, 4718592)     dead after rank_decode
    //   counts [4718592, 4722688)     32*CPAD u32 — dead after rank_decode
    //   tbin   [4722688, 4722816)     dead after compact
    //   sscore [9216000, 9408000)
    //   sbox   [9408000, 10176000)    total 10,176,000 B
    u64* mask_buf = (u64*)(ws + 0);
    u32* hist     = (u32*)(ws + 0);
    u64* keys     = (u64*)(ws + 4194304);
    u32* counts   = (u32*)(ws + 4718592);
    int* tbin     = (int*)(ws + 4722688);
    float* sscore = (float*)(ws + 9216000);
    float* sbox   = (float*)(ws + 9408000);

    // zero: counts, out, and sscore+sbox (contiguous 960000 floats) for the
    // (never-hit-here) n < TOPK case where some rank rows go unwritten.
    zero_kernel<<<512, 256, 0, stream>>>(counts, NUM_B * CPAD, (u32*)out, 480000,
                                         (u32*)sscore, 240000);
    hist_kernel<<<dim3(HSLICES, 32), 256, 0, stream>>>((const float4*)conf, hist);
    thresh_kernel<<<32, 256, 0, stream>>>(hist, tbin);
    compact_kernel<<<dim3(150, 32), 256, 0, stream>>>((const float4*)conf, tbin, counts, keys);
    rank_decode_kernel<<<dim3(CAP / 256, 32), 256, 0, stream>>>(keys, counts, loc, prior,
                                                                sscore, sbox);
    mask_kernel<<<dim3(NWORDS, 32), 256, 0, stream>>>(sbox, mask_buf);
    sweep_kernel<<<32, 64, 0, stream>>>(mask_buf, sscore, sbox, out);
}

// Round 9
// 235.511 us; speedup vs baseline: 3.9774x; 1.1799x over previous
//
#include <hip/hip_runtime.h>
#include <stdint.h>

typedef unsigned long long u64;
typedef unsigned int u32;

#define NUM_B 32
#define NUM_P 76800
#define TOPK 1500
#define NBINS 4096   // linear bins: bin = min(int(s*4096), 4095)
#define CAP 2048
#define NWORDS 24    // ceil(1500/64) u64 words per mask row == number of 64-row tiles
#define CPAD 32      // counts padded to 128 B to kill same-line atomic serialization
#define HSLICES 8    // private histogram slices per batch (no global atomics)
#define HCHUNK (NUM_P / HSLICES)   // 9600 priors per slice

__device__ __forceinline__ u32 fbits(float f) { return __float_as_uint(f); }
// Monotone non-decreasing in s => threshold-bin selection is order-correct.
__device__ __forceinline__ int binOf(float s) {
    int b = (int)(s * (float)NBINS);
    return (b > NBINS - 1) ? NBINS - 1 : b;
}
// wave-uniform lane read of a u64 register
__device__ __forceinline__ u64 readlane64(u64 v, int l) {
    u32 lo = (u32)__builtin_amdgcn_readlane((int)(u32)(v & 0xffffffffu), l);
    u32 hi = (u32)__builtin_amdgcn_readlane((int)(u32)(v >> 32), l);
    return ((u64)hi << 32) | lo;
}

// ---------------- zero counts + output + sscore/sbox ----------------
__global__ void zero_kernel(u32* a, int n, u32* c, int nc, u32* d, int nd) {
    int i = blockIdx.x * blockDim.x + threadIdx.x;
    int stride = gridDim.x * blockDim.x;
    for (int t = i; t < n; t += stride) a[t] = 0;
    for (int t = i; t < nc; t += stride) c[t] = 0;
    for (int t = i; t < nd; t += stride) d[t] = 0;
}

// ---------------- histogram: LDS-private per (batch, slice), full overwrite ----------------
__global__ __launch_bounds__(256) void hist_kernel(const float4* __restrict__ conf4,
                                                   u32* __restrict__ hist) {
    int c = blockIdx.x, b = blockIdx.y, tid = threadIdx.x;
    __shared__ u32 h[NBINS];
    for (int i = tid; i < NBINS; i += 256) h[i] = 0;
    __syncthreads();
    const float4* base = conf4 + (size_t)b * (NUM_P / 2) + (size_t)c * (HCHUNK / 2);
    for (int i = tid; i < HCHUNK / 2; i += 256) {
        float4 v = base[i];           // 2 priors: (c0,c1,c0,c1); class-1 = .y/.w
        if (v.y > 0.01f) atomicAdd(&h[binOf(v.y)], 1u);
        if (v.w > 0.01f) atomicAdd(&h[binOf(v.w)], 1u);
    }
    __syncthreads();
    u32* outp = hist + ((size_t)b * HSLICES + c) * NBINS;
    for (int i = tid; i < NBINS; i += 256) outp[i] = h[i];
}

// ---------------- find per-batch threshold bin: smallest bin T with suffix count >= TOPK ----
__global__ void thresh_kernel(const u32* __restrict__ hist, int* __restrict__ tbin) {
    int b = blockIdx.x;
    int tid = threadIdx.x;
    const u32* hb = hist + (size_t)b * HSLICES * NBINS;
    __shared__ u32 vals[256];
    __shared__ int s_min;
    u32 total = 0;
    for (int c = 0; c < NBINS / 256; ++c) {
        if (tid == 0) s_min = 256;
        int bin = NBINS - 1 - (c * 256 + tid);
        u32 v = 0;
#pragma unroll
        for (int s = 0; s < HSLICES; ++s) v += hb[(size_t)s * NBINS + bin];
        __syncthreads();
        vals[tid] = v;
        __syncthreads();
        for (int off = 1; off < 256; off <<= 1) {
            u32 add = (tid >= off) ? vals[tid - off] : 0;
            __syncthreads();
            vals[tid] += add;
            __syncthreads();
        }
        u32 cum = total + vals[tid];
        if (cum >= TOPK) atomicMin(&s_min, tid);
        __syncthreads();
        if (s_min < 256) {
            if (tid == 0) tbin[b] = NBINS - 1 - (c * 256 + s_min);
            return;
        }
        total += vals[255];
    }
    if (tid == 0) tbin[b] = 0;
}

// ---------------- compact candidate keys: float4 loads, padded counters ----------------
__global__ __launch_bounds__(256) void compact_kernel(
    const float4* __restrict__ conf4, const int* __restrict__ tbin,
    u32* __restrict__ counts, u64* __restrict__ keys) {
    int b = blockIdx.y;
    int tid = threadIdx.x;
    int lane = tid & 63, wave = tid >> 6;
    int f4 = blockIdx.x * 256 + tid;            // float4 index within batch (2 priors)
    float4 c = conf4[(size_t)b * (NUM_P / 2) + f4];
    int tb = tbin[b];
    int p0 = f4 * 2, p1 = p0 + 1;
    bool v0 = (c.y > 0.01f) && (binOf(c.y) >= tb);
    bool v1 = (c.w > 0.01f) && (binOf(c.w) >= tb);

    u64 m0 = __ballot(v0), m1 = __ballot(v1);
    u32 c0 = (u32)__popcll(m0);
    u64 below = (1ULL << lane) - 1ULL;
    u32 off0 = (u32)__popcll(m0 & below);
    u32 off1 = c0 + (u32)__popcll(m1 & below);
    u32 wtot = c0 + (u32)__popcll(m1);

    __shared__ u32 wcnt[4];
    __shared__ u32 s_base;
    if (lane == 0) wcnt[wave] = wtot;
    __syncthreads();
    if (tid == 0) {
        u32 tot = wcnt[0] + wcnt[1] + wcnt[2] + wcnt[3];
        s_base = (tot > 0) ? atomicAdd(&counts[(size_t)b * CPAD], tot) : 0u;
    }
    __syncthreads();
    u32 woff = 0;
    for (int w = 0; w < wave; ++w) woff += wcnt[w];
    if (v0) {
        u32 pos = s_base + woff + off0;
        if (pos < CAP) keys[(size_t)b * CAP + pos] = ((u64)fbits(c.y) << 32) | (u32)(~p0);
    }
    if (v1) {
        u32 pos = s_base + woff + off1;
        if (pos < CAP) keys[(size_t)b * CAP + pos] = ((u64)fbits(c.w) << 32) | (u32)(~p1);
    }
}

// ---------------- rank-by-count (replaces bitonic sort) + gather+decode boxes ----------
__global__ __launch_bounds__(256) void rank_decode_kernel(
    const u64* __restrict__ keys, const u32* __restrict__ counts,
    const float* __restrict__ loc, const float* __restrict__ prior,
    float* __restrict__ sscore, float* __restrict__ sbox) {
#pragma clang fp contract(off)
    int blk = blockIdx.x, b = blockIdx.y, tid = threadIdx.x;
    __shared__ u64 k[CAP];
    int n = (int)min(counts[(size_t)b * CPAD], (u32)CAP);
    for (int t = tid; t < CAP; t += 256)
        k[t] = (t < n) ? keys[(size_t)b * CAP + t] : 0ULL;
    __syncthreads();

    int t = blk * 256 + tid;
    u64 mykey = k[t];
    if (mykey == 0ULL) return;   // empty slot (valid keys have score bits != 0)

    u32 rank = 0;
#pragma unroll 8
    for (int j = 0; j < CAP; ++j) rank += (k[j] > mykey) ? 1u : 0u;

    if (rank < TOPK) {
        u32 pidx = ~(u32)mykey;
        float sc = __uint_as_float((u32)(mykey >> 32));
        const float* lp = &loc[((size_t)b * NUM_P + pidx) * 4];
        const float* pp = &prior[(size_t)pidx * 4];
        float lx = lp[0], ly = lp[1], lw = lp[2], lh = lp[3];
        float pcx = pp[0], pcy = pp[1], pw = pp[2], ph = pp[3];
        float cx = pcx + (lx * 0.1f) * pw;
        float cy = pcy + (ly * 0.1f) * ph;
        float w  = pw * expf(lw * 0.2f);
        float h  = ph * expf(lh * 0.2f);
        float x1 = cx - w * 0.5f;
        float y1 = cy - h * 0.5f;
        float x2 = x1 + w;
        float y2 = y1 + h;
        sscore[(size_t)b * TOPK + rank] = sc;
        float* bx = &sbox[((size_t)b * TOPK + rank) * 4];
        bx[0] = x1; bx[1] = y1; bx[2] = x2; bx[3] = y2;
    }
}

// ---------------- NMS phase 1: suppression bitmask, fully parallel ----------------
__global__ __launch_bounds__(256) void mask_kernel(
    const float* __restrict__ sbox, u64* __restrict__ mask) {
#pragma clang fp contract(off)
    int w = blockIdx.x, b = blockIdx.y, tid = threadIdx.x;
    __shared__ float4 cbox[64];
    __shared__ float car[64];
    if (tid < 64) {
        int j = w * 64 + tid;
        float4 bx = make_float4(0.f, 0.f, 0.f, 0.f);
        if (j < TOPK) bx = ((const float4*)sbox)[(size_t)b * TOPK + j];
        cbox[tid] = bx;
        car[tid] = (bx.z - bx.x) * (bx.w - bx.y);
    }
    __syncthreads();
    for (int i = tid; i < TOPK; i += 256) {
        u64 m = 0;
        if (w * 64 + 63 > i) {  // word has at least one j > i
            const float4 bx = ((const float4*)sbox)[(size_t)b * TOPK + i];
            float x1i = bx.x, y1i = bx.y, x2i = bx.z, y2i = bx.w;
            float ai = (x2i - x1i) * (y2i - y1i);
            for (int j2 = 0; j2 < 64; ++j2) {
                int j = w * 64 + j2;
                float4 cb = cbox[j2];
                float xx1 = fmaxf(cb.x, x1i);
                float yy1 = fmaxf(cb.y, y1i);
                float xx2 = fminf(cb.z, x2i);
                float yy2 = fminf(cb.w, y2i);
                float iw = fmaxf(xx2 - xx1, 0.0f);
                float ih = fmaxf(yy2 - yy1, 0.0f);
                float inter = iw * ih;
                float iou = inter / ((car[j2] + ai) - inter);
                if ((iou > 0.2f) && (j > i)) m |= (1ULL << j2);
            }
        }
        mask[((size_t)b * TOPK + i) * NWORDS + w] = m;
    }
}

// ---------------- NMS phase 2: tiled serial sweep, one wave per batch ----------------
// All global loads are tile-indexed (speculative), never kept-indexed: lane r
// prefetches full mask row T*64+r (24 u64, contiguous) into registers, double-
// buffered 2 tiles ahead. Greedy uses buf[T] as diag (readlane). Kept lanes dump
// their resident rows to LDS; apply is pipelined ds_read_b64. Zero dependent
// global round-trips on the critical path.
__global__ __launch_bounds__(64) void sweep_kernel(
    const u64* __restrict__ mask, const float* __restrict__ sscore,
    const float* __restrict__ sbox, float* __restrict__ out) {
    int b = blockIdx.x, lane = threadIdx.x;

    // initial active bitmap from validity (score > 0); lane w owns act word w
    u64 act = 0;
    for (int c = 0; c < NWORDS; ++c) {
        int r = c * 64 + lane;
        bool v = (r < TOPK) && (sscore[(size_t)b * TOPK + r] > 0.0f);
        u64 m = __ballot(v);
        if (lane == c) act = m;
    }

    int lw = (lane < NWORDS) ? lane : 0;   // lanes >= NWORDS shadow word 0 (their act==0)
    const u64* mbase = mask + (size_t)b * TOPK * NWORDS;

    __shared__ u64 ldsrow[64][NWORDS];

    u64 bufA[NWORDS], bufB[NWORDS];
    {   // preload tiles 0 and 1
        int r0 = lane;                     // always < TOPK
        const u64* rp0 = mbase + (size_t)r0 * NWORDS;
#pragma unroll
        for (int w = 0; w < NWORDS; ++w) bufA[w] = rp0[w];
        int r1 = 64 + lane;
        const u64* rp1 = mbase + (size_t)r1 * NWORDS;
#pragma unroll
        for (int w = 0; w < NWORDS; ++w) bufB[w] = rp1[w];
    }

#define PROCESS_TILE(T, CUR, NXT)                                              \
    {                                                                          \
        u64 diag = CUR[(T)];                                                   \
        u64 actw = readlane64(act, (T));                                       \
        u64 kept = 0, rem = actw;                                              \
        while (rem) {                                                          \
            int i = __ffsll(rem) - 1;                                          \
            kept |= (1ULL << i);                                               \
            rem &= rem - 1;                                                    \
            rem &= ~readlane64(diag, i);                                       \
        }                                                                      \
        if (lane == (T)) act = kept;                                           \
        if ((kept >> lane) & 1ULL) {                                           \
            _Pragma("unroll")                                                  \
            for (int w = 0; w < NWORDS; ++w) ldsrow[lane][w] = CUR[w];         \
        }                                                                      \
        __syncthreads();                                                       \
        if ((NXT) < NWORDS) {  /* speculative prefetch, overwrites dead CUR */ \
            int rr = (NXT) * 64 + lane;                                        \
            const u64* rp = mbase + (size_t)rr * NWORDS;                       \
            if (rr < TOPK) {                                                   \
                _Pragma("unroll")                                              \
                for (int w = 0; w < NWORDS; ++w) CUR[w] = rp[w];               \
            } else {                                                           \
                _Pragma("unroll")                                              \
                for (int w = 0; w < NWORDS; ++w) CUR[w] = 0ULL;                \
            }                                                                  \
        }                                                                      \
        u64 kb = kept;                                                         \
        while (kb) {                                                           \
            int r = __ffsll(kb) - 1;                                           \
            kb &= kb - 1;                                                      \
            act &= ~ldsrow[r][lw];                                             \
        }                                                                      \
        __syncthreads();                                                       \
    }

#pragma unroll
    for (int k = 0; k < NWORDS; k += 2) {
        PROCESS_TILE(k, bufA, k + 2);
        PROCESS_TILE(k + 1, bufB, k + 3);
    }
#undef PROCESS_TILE

    // epilogue: act == keep bitmap; rank by prefix popcount, write compacted rows
    __shared__ u64 aw[NWORDS];
    __shared__ u32 pfx[NWORDS + 1];
    if (lane < NWORDS) aw[lane] = act;
    __syncthreads();
    if (lane == 0) {
        u32 acc = 0;
        for (int wd = 0; wd < NWORDS; ++wd) { pfx[wd] = acc; acc += (u32)__popcll(aw[wd]); }
        pfx[NWORDS] = acc;
    }
    __syncthreads();
    for (int r = lane; r < TOPK; r += 64) {
        int wd = r >> 6;
        u64 word = aw[wd];
        if ((word >> (r & 63)) & 1ULL) {
            u32 rank = pfx[wd] + (u32)__popcll(word & ((1ULL << (r & 63)) - 1ULL));
            float sc = sscore[(size_t)b * TOPK + r];
            float4 bx = ((const float4*)sbox)[(size_t)b * TOPK + r];
            size_t base_o = (((size_t)b * 2 + 1) * TOPK + (size_t)rank) * 5;
            out[base_o + 0] = sc;
            out[base_o + 1] = bx.x;
            out[base_o + 2] = bx.y;
            out[base_o + 3] = bx.z;
            out[base_o + 4] = bx.w;
        }
    }
}

extern "C" void kernel_launch(void* const* d_in, const int* in_sizes, int n_in,
                              void* d_out, int out_size, void* d_ws, size_t ws_size,
                              hipStream_t stream) {
    const float* loc   = (const float*)d_in[0];
    const float* conf  = (const float*)d_in[1];
    const float* prior = (const float*)d_in[2];
    float* out = (float*)d_out;
    char* ws = (char*)d_ws;

    // ws layout (bytes) with lifetime-based aliasing into the mask region:
    //   mask   [0, 9216000)           written by mask_kernel, read by sweep
    //   hist   [0, 4194304)           32*8*4096 u32 — dead after thresh (full overwrite)
    //   keys   [4194304, 4718592)     dead after rank_decode
    //   counts [4718592, 4722688)     32*CPAD u32 — dead after rank_decode
    //   tbin   [4722688, 4722816)     dead after compact
    //   sscore [9216000, 9408000)
    //   sbox   [9408000, 10176000)    total 10,176,000 B
    u64* mask_buf = (u64*)(ws + 0);
    u32* hist     = (u32*)(ws + 0);
    u64* keys     = (u64*)(ws + 4194304);
    u32* counts   = (u32*)(ws + 4718592);
    int* tbin     = (int*)(ws + 4722688);
    float* sscore = (float*)(ws + 9216000);
    float* sbox   = (float*)(ws + 9408000);

    zero_kernel<<<512, 256, 0, stream>>>(counts, NUM_B * CPAD, (u32*)out, 480000,
                                         (u32*)sscore, 240000);
    hist_kernel<<<dim3(HSLICES, 32), 256, 0, stream>>>((const float4*)conf, hist);
    thresh_kernel<<<32, 256, 0, stream>>>(hist, tbin);
    compact_kernel<<<dim3(150, 32), 256, 0, stream>>>((const float4*)conf, tbin, counts, keys);
    rank_decode_kernel<<<dim3(CAP / 256, 32), 256, 0, stream>>>(keys, counts, loc, prior,
                                                                sscore, sbox);
    mask_kernel<<<dim3(NWORDS, 32), 256, 0, stream>>>(sbox, mask_buf);
    sweep_kernel<<<32, 64, 0, stream>>>(mask_buf, sscore, sbox, out);
}

// Round 10
// 222.756 us; speedup vs baseline: 4.2052x; 1.0573x over previous
//
#include <hip/hip_runtime.h>
#include <stdint.h>

typedef unsigned long long u64;
typedef unsigned int u32;

#define NUM_B 32
#define NUM_P 76800
#define TOPK 1500
#define NBINS 4096   // linear bins: bin = min(int(s*4096), 4095)
#define CAP 2048
#define NWORDS 24    // ceil(1500/64) u64 words per mask row == number of 64-row tiles
#define NCHUNK 6     // ceil(1500/256) row chunks for mask grid
#define CPAD 32      // counts padded to 128 B to kill same-line atomic serialization
#define HSLICES 8    // private histogram slices per batch (no global atomics)
#define HCHUNK (NUM_P / HSLICES)   // 9600 priors per slice

__device__ __forceinline__ u32 fbits(float f) { return __float_as_uint(f); }
// Monotone non-decreasing in s => threshold-bin selection is order-correct.
__device__ __forceinline__ int binOf(float s) {
    int b = (int)(s * (float)NBINS);
    return (b > NBINS - 1) ? NBINS - 1 : b;
}
// wave-uniform lane read of a u64 register
__device__ __forceinline__ u64 readlane64(u64 v, int l) {
    u32 lo = (u32)__builtin_amdgcn_readlane((int)(u32)(v & 0xffffffffu), l);
    u32 hi = (u32)__builtin_amdgcn_readlane((int)(u32)(v >> 32), l);
    return ((u64)hi << 32) | lo;
}

// ---------------- zero counts + output + sscore/sbox ----------------
__global__ void zero_kernel(u32* a, int n, u32* c, int nc, u32* d, int nd) {
    int i = blockIdx.x * blockDim.x + threadIdx.x;
    int stride = gridDim.x * blockDim.x;
    for (int t = i; t < n; t += stride) a[t] = 0;
    for (int t = i; t < nc; t += stride) c[t] = 0;
    for (int t = i; t < nd; t += stride) d[t] = 0;
}

// ---------------- histogram: LDS-private per (batch, slice), full overwrite ----------------
__global__ __launch_bounds__(256) void hist_kernel(const float4* __restrict__ conf4,
                                                   u32* __restrict__ hist) {
    int c = blockIdx.x, b = blockIdx.y, tid = threadIdx.x;
    __shared__ u32 h[NBINS];
    for (int i = tid; i < NBINS; i += 256) h[i] = 0;
    __syncthreads();
    const float4* base = conf4 + (size_t)b * (NUM_P / 2) + (size_t)c * (HCHUNK / 2);
    for (int i = tid; i < HCHUNK / 2; i += 256) {
        float4 v = base[i];           // 2 priors: (c0,c1,c0,c1); class-1 = .y/.w
        if (v.y > 0.01f) atomicAdd(&h[binOf(v.y)], 1u);
        if (v.w > 0.01f) atomicAdd(&h[binOf(v.w)], 1u);
    }
    __syncthreads();
    u32* outp = hist + ((size_t)b * HSLICES + c) * NBINS;
    for (int i = tid; i < NBINS; i += 256) outp[i] = h[i];
}

// ---------------- find per-batch threshold bin: smallest bin T with suffix count >= TOPK ----
__global__ void thresh_kernel(const u32* __restrict__ hist, int* __restrict__ tbin) {
    int b = blockIdx.x;
    int tid = threadIdx.x;
    const u32* hb = hist + (size_t)b * HSLICES * NBINS;
    __shared__ u32 vals[256];
    __shared__ int s_min;
    u32 total = 0;
    for (int c = 0; c < NBINS / 256; ++c) {
        if (tid == 0) s_min = 256;
        int bin = NBINS - 1 - (c * 256 + tid);
        u32 v = 0;
#pragma unroll
        for (int s = 0; s < HSLICES; ++s) v += hb[(size_t)s * NBINS + bin];
        __syncthreads();
        vals[tid] = v;
        __syncthreads();
        for (int off = 1; off < 256; off <<= 1) {
            u32 add = (tid >= off) ? vals[tid - off] : 0;
            __syncthreads();
            vals[tid] += add;
            __syncthreads();
        }
        u32 cum = total + vals[tid];
        if (cum >= TOPK) atomicMin(&s_min, tid);
        __syncthreads();
        if (s_min < 256) {
            if (tid == 0) tbin[b] = NBINS - 1 - (c * 256 + s_min);
            return;
        }
        total += vals[255];
    }
    if (tid == 0) tbin[b] = 0;
}

// ---------------- compact candidate keys: float4 loads, padded counters ----------------
__global__ __launch_bounds__(256) void compact_kernel(
    const float4* __restrict__ conf4, const int* __restrict__ tbin,
    u32* __restrict__ counts, u64* __restrict__ keys) {
    int b = blockIdx.y;
    int tid = threadIdx.x;
    int lane = tid & 63, wave = tid >> 6;
    int f4 = blockIdx.x * 256 + tid;            // float4 index within batch (2 priors)
    float4 c = conf4[(size_t)b * (NUM_P / 2) + f4];
    int tb = tbin[b];
    int p0 = f4 * 2, p1 = p0 + 1;
    bool v0 = (c.y > 0.01f) && (binOf(c.y) >= tb);
    bool v1 = (c.w > 0.01f) && (binOf(c.w) >= tb);

    u64 m0 = __ballot(v0), m1 = __ballot(v1);
    u32 c0 = (u32)__popcll(m0);
    u64 below = (1ULL << lane) - 1ULL;
    u32 off0 = (u32)__popcll(m0 & below);
    u32 off1 = c0 + (u32)__popcll(m1 & below);
    u32 wtot = c0 + (u32)__popcll(m1);

    __shared__ u32 wcnt[4];
    __shared__ u32 s_base;
    if (lane == 0) wcnt[wave] = wtot;
    __syncthreads();
    if (tid == 0) {
        u32 tot = wcnt[0] + wcnt[1] + wcnt[2] + wcnt[3];
        s_base = (tot > 0) ? atomicAdd(&counts[(size_t)b * CPAD], tot) : 0u;
    }
    __syncthreads();
    u32 woff = 0;
    for (int w = 0; w < wave; ++w) woff += wcnt[w];
    if (v0) {
        u32 pos = s_base + woff + off0;
        if (pos < CAP) keys[(size_t)b * CAP + pos] = ((u64)fbits(c.y) << 32) | (u32)(~p0);
    }
    if (v1) {
        u32 pos = s_base + woff + off1;
        if (pos < CAP) keys[(size_t)b * CAP + pos] = ((u64)fbits(c.w) << 32) | (u32)(~p1);
    }
}

// ---------------- rank-by-count (replaces bitonic sort) + gather+decode boxes ----------
__global__ __launch_bounds__(256) void rank_decode_kernel(
    const u64* __restrict__ keys, const u32* __restrict__ counts,
    const float* __restrict__ loc, const float* __restrict__ prior,
    float* __restrict__ sscore, float* __restrict__ sbox) {
#pragma clang fp contract(off)
    int blk = blockIdx.x, b = blockIdx.y, tid = threadIdx.x;
    __shared__ u64 k[CAP];
    int n = (int)min(counts[(size_t)b * CPAD], (u32)CAP);
    for (int t = tid; t < CAP; t += 256)
        k[t] = (t < n) ? keys[(size_t)b * CAP + t] : 0ULL;
    __syncthreads();

    int t = blk * 256 + tid;
    u64 mykey = k[t];
    if (mykey == 0ULL) return;   // empty slot (valid keys have score bits != 0)

    u32 rank = 0;
#pragma unroll 8
    for (int j = 0; j < CAP; ++j) rank += (k[j] > mykey) ? 1u : 0u;

    if (rank < TOPK) {
        u32 pidx = ~(u32)mykey;
        float sc = __uint_as_float((u32)(mykey >> 32));
        const float* lp = &loc[((size_t)b * NUM_P + pidx) * 4];
        const float* pp = &prior[(size_t)pidx * 4];
        float lx = lp[0], ly = lp[1], lw = lp[2], lh = lp[3];
        float pcx = pp[0], pcy = pp[1], pw = pp[2], ph = pp[3];
        float cx = pcx + (lx * 0.1f) * pw;
        float cy = pcy + (ly * 0.1f) * ph;
        float w  = pw * expf(lw * 0.2f);
        float h  = ph * expf(lh * 0.2f);
        float x1 = cx - w * 0.5f;
        float y1 = cy - h * 0.5f;
        float x2 = x1 + w;
        float y2 = y1 + h;
        sscore[(size_t)b * TOPK + rank] = sc;
        float* bx = &sbox[((size_t)b * TOPK + rank) * 4];
        bx[0] = x1; bx[1] = y1; bx[2] = x2; bx[3] = y2;
    }
}

// ---------------- NMS phase 1: suppression bitmask — transposed + balanced ----------------
// Layout: mask_t[b][w][i] (consecutive rows i contiguous -> coalesced 8B stores &
// coalesced sweep reads). Grid (w, chunk, b): one row per thread, every compute
// block has identical cost; fully-culled blocks just write zeros.
__global__ __launch_bounds__(256) void mask_kernel(
    const float* __restrict__ sbox, u64* __restrict__ mask) {
#pragma clang fp contract(off)
    int w = blockIdx.x, c = blockIdx.y, b = blockIdx.z, tid = threadIdx.x;
    int i = c * 256 + tid;
    __shared__ float4 cbox[64];
    __shared__ float car[64];
    bool blk_live = (w * 64 + 63) > (c * 256);   // any row in chunk needs this word
    if (blk_live) {
        if (tid < 64) {
            int j = w * 64 + tid;
            float4 bx = make_float4(0.f, 0.f, 0.f, 0.f);
            if (j < TOPK) bx = ((const float4*)sbox)[(size_t)b * TOPK + j];
            cbox[tid] = bx;
            car[tid] = (bx.z - bx.x) * (bx.w - bx.y);
        }
        __syncthreads();
    }
    u64 m = 0;
    if (blk_live && i < TOPK && (w * 64 + 63) > i) {
        const float4 bx = ((const float4*)sbox)[(size_t)b * TOPK + i];
        float x1i = bx.x, y1i = bx.y, x2i = bx.z, y2i = bx.w;
        float ai = (x2i - x1i) * (y2i - y1i);
        for (int j2 = 0; j2 < 64; ++j2) {
            int j = w * 64 + j2;
            float4 cb = cbox[j2];
            float xx1 = fmaxf(cb.x, x1i);
            float yy1 = fmaxf(cb.y, y1i);
            float xx2 = fminf(cb.z, x2i);
            float yy2 = fminf(cb.w, y2i);
            float iw = fmaxf(xx2 - xx1, 0.0f);
            float ih = fmaxf(yy2 - yy1, 0.0f);
            float inter = iw * ih;
            float iou = inter / ((car[j2] + ai) - inter);
            if ((iou > 0.2f) && (j > i)) m |= (1ULL << j2);
        }
    }
    if (i < TOPK)
        mask[((size_t)b * NWORDS + w) * TOPK + i] = m;
}

// ---------------- NMS phase 2: tiled serial sweep, one wave per batch ----------------
// All global loads are tile-indexed (speculative), never kept-indexed: lane r
// prefetches full mask row T*64+r (24 words, now coalesced per word across the
// wave) into registers, double-buffered 2 tiles ahead. Greedy uses buf[T] as
// diag (readlane). Kept lanes dump resident rows to LDS; apply is ds_read_b64.
__global__ __launch_bounds__(64) void sweep_kernel(
    const u64* __restrict__ mask, const float* __restrict__ sscore,
    const float* __restrict__ sbox, float* __restrict__ out) {
    int b = blockIdx.x, lane = threadIdx.x;

    // initial active bitmap from validity (score > 0); lane w owns act word w
    u64 act = 0;
    for (int c = 0; c < NWORDS; ++c) {
        int r = c * 64 + lane;
        bool v = (r < TOPK) && (sscore[(size_t)b * TOPK + r] > 0.0f);
        u64 m = __ballot(v);
        if (lane == c) act = m;
    }

    int lw = (lane < NWORDS) ? lane : 0;   // lanes >= NWORDS shadow word 0 (their act==0)
    const u64* mbase = mask + (size_t)b * NWORDS * TOPK;   // word w, row r: mbase[w*TOPK+r]

    __shared__ u64 ldsrow[64][NWORDS];

    u64 bufA[NWORDS], bufB[NWORDS];
    {   // preload tiles 0 and 1 (rows lane, 64+lane — always < TOPK)
#pragma unroll
        for (int w = 0; w < NWORDS; ++w) bufA[w] = mbase[(size_t)w * TOPK + lane];
#pragma unroll
        for (int w = 0; w < NWORDS; ++w) bufB[w] = mbase[(size_t)w * TOPK + 64 + lane];
    }

#define PROCESS_TILE(T, CUR, NXT)                                              \
    {                                                                          \
        u64 diag = CUR[(T)];                                                   \
        u64 actw = readlane64(act, (T));                                       \
        u64 kept = 0, rem = actw;                                              \
        while (rem) {                                                          \
            int i = __ffsll(rem) - 1;                                          \
            kept |= (1ULL << i);                                               \
            rem &= rem - 1;                                                    \
            rem &= ~readlane64(diag, i);                                       \
        }                                                                      \
        if (lane == (T)) act = kept;                                           \
        if ((kept >> lane) & 1ULL) {                                           \
            _Pragma("unroll")                                                  \
            for (int w = 0; w < NWORDS; ++w) ldsrow[lane][w] = CUR[w];         \
        }                                                                      \
        __syncthreads();                                                       \
        if ((NXT) < NWORDS) {  /* speculative prefetch, overwrites dead CUR */ \
            int rr = (NXT) * 64 + lane;                                        \
            if (rr < TOPK) {                                                   \
                _Pragma("unroll")                                              \
                for (int w = 0; w < NWORDS; ++w)                               \
                    CUR[w] = mbase[(size_t)w * TOPK + rr];                     \
            } else {                                                           \
                _Pragma("unroll")                                              \
                for (int w = 0; w < NWORDS; ++w) CUR[w] = 0ULL;                \
            }                                                                  \
        }                                                                      \
        u64 kb = kept;                                                         \
        while (kb) {                                                           \
            int r = __ffsll(kb) - 1;                                           \
            kb &= kb - 1;                                                      \
            act &= ~ldsrow[r][lw];                                             \
        }                                                                      \
        __syncthreads();                                                       \
    }

#pragma unroll
    for (int k = 0; k < NWORDS; k += 2) {
        PROCESS_TILE(k, bufA, k + 2);
        PROCESS_TILE(k + 1, bufB, k + 3);
    }
#undef PROCESS_TILE

    // epilogue: act == keep bitmap; rank by prefix popcount, write compacted rows
    __shared__ u64 aw[NWORDS];
    __shared__ u32 pfx[NWORDS + 1];
    if (lane < NWORDS) aw[lane] = act;
    __syncthreads();
    if (lane == 0) {
        u32 acc = 0;
        for (int wd = 0; wd < NWORDS; ++wd) { pfx[wd] = acc; acc += (u32)__popcll(aw[wd]); }
        pfx[NWORDS] = acc;
    }
    __syncthreads();
    for (int r = lane; r < TOPK; r += 64) {
        int wd = r >> 6;
        u64 word = aw[wd];
        if ((word >> (r & 63)) & 1ULL) {
            u32 rank = pfx[wd] + (u32)__popcll(word & ((1ULL << (r & 63)) - 1ULL));
            float sc = sscore[(size_t)b * TOPK + r];
            float4 bx = ((const float4*)sbox)[(size_t)b * TOPK + r];
            size_t base_o = (((size_t)b * 2 + 1) * TOPK + (size_t)rank) * 5;
            out[base_o + 0] = sc;
            out[base_o + 1] = bx.x;
            out[base_o + 2] = bx.y;
            out[base_o + 3] = bx.z;
            out[base_o + 4] = bx.w;
        }
    }
}

extern "C" void kernel_launch(void* const* d_in, const int* in_sizes, int n_in,
                              void* d_out, int out_size, void* d_ws, size_t ws_size,
                              hipStream_t stream) {
    const float* loc   = (const float*)d_in[0];
    const float* conf  = (const float*)d_in[1];
    const float* prior = (const float*)d_in[2];
    float* out = (float*)d_out;
    char* ws = (char*)d_ws;

    // ws layout (bytes) with lifetime-based aliasing into the mask region:
    //   mask   [0, 9216000)           transposed [b][w][i]; written by mask, read by sweep
    //   hist   [0, 4194304)           32*8*4096 u32 — dead after thresh (full overwrite)
    //   keys   [4194304, 4718592)     dead after rank_decode
    //   counts [4718592, 4722688)     32*CPAD u32 — dead after rank_decode
    //   tbin   [4722688, 4722816)     dead after compact
    //   sscore [9216000, 9408000)
    //   sbox   [9408000, 10176000)    total 10,176,000 B
    u64* mask_buf = (u64*)(ws + 0);
    u32* hist     = (u32*)(ws + 0);
    u64* keys     = (u64*)(ws + 4194304);
    u32* counts   = (u32*)(ws + 4718592);
    int* tbin     = (int*)(ws + 4722688);
    float* sscore = (float*)(ws + 9216000);
    float* sbox   = (float*)(ws + 9408000);

    zero_kernel<<<512, 256, 0, stream>>>(counts, NUM_B * CPAD, (u32*)out, 480000,
                                         (u32*)sscore, 240000);
    hist_kernel<<<dim3(HSLICES, 32), 256, 0, stream>>>((const float4*)conf, hist);
    thresh_kernel<<<32, 256, 0, stream>>>(hist, tbin);
    compact_kernel<<<dim3(150, 32), 256, 0, stream>>>((const float4*)conf, tbin, counts, keys);
    rank_decode_kernel<<<dim3(CAP / 256, 32), 256, 0, stream>>>(keys, counts, loc, prior,
                                                                sscore, sbox);
    mask_kernel<<<dim3(NWORDS, NCHUNK, 32), 256, 0, stream>>>(sbox, mask_buf);
    sweep_kernel<<<32, 64, 0, stream>>>(mask_buf, sscore, sbox, out);
}